// Round 1
// baseline (733.204 us; speedup 1.0000x reference)
//
#include <hip/hip_runtime.h>
#include <hip/hip_bf16.h>
#include <cfloat>

#define N1C 50176
#define N2C 12544
#define N3C 3136
#define BC  16
#define KC  9
#define TC  9

// ---------------- transpose x: (B,3,N1) -> xT (N1, 3, 16) ----------------
__global__ __launch_bounds__(256) void transpose_x_kernel(
    const float* __restrict__ x, float* __restrict__ xT)
{
  __shared__ float tile[48][65];
  int n0 = blockIdx.x * 64;
  int tid = threadIdx.x;
  int i = tid & 63;
  for (int rr = tid >> 6; rr < 48; rr += 4){
    int b = rr / 3, c = rr % 3;            // x row rr = b*3 + c
    tile[c*16 + b][i] = x[(size_t)rr * N1C + n0 + i];
  }
  __syncthreads();
  for (int j = tid; j < 48*64; j += 256){
    int ii = j / 48, cb = j % 48;
    xT[(size_t)n0 * 48 + j] = tile[cb][ii];   // xT[(n0+ii)*48 + cb]
  }
}

// ---------------- A[n,k,t] = (relu(off @ w1 + b1) @ w2 + b2) ----------------
__global__ __launch_bounds__(256) void compute_A_kernel(
    const float* __restrict__ pos_in, const float* __restrict__ pos_out,
    const int* __restrict__ idx,
    const float* __restrict__ w1, const float* __restrict__ b1,
    const float* __restrict__ w2, const float* __restrict__ b2,
    float* __restrict__ Abuf)
{
  int g = blockIdx.x * 256 + threadIdx.x;
  if (g >= N2C * KC) return;
  int n = g / KC;
  int p = idx[g];
  float o0 = pos_in[2*p]   - pos_out[2*n];
  float o1 = pos_in[2*p+1] - pos_out[2*n+1];
  float A[TC];
  #pragma unroll
  for (int t = 0; t < TC; t++) A[t] = b2[t];
  #pragma unroll
  for (int j = 0; j < 16; j++){
    float h = fmaxf(fmaf(o0, w1[j], fmaf(o1, w1[16+j], b1[j])), 0.f);
    #pragma unroll
    for (int t = 0; t < TC; t++) A[t] = fmaf(h, w2[j*TC + t], A[t]);
  }
  #pragma unroll
  for (int t = 0; t < TC; t++) Abuf[(size_t)g*TC + t] = A[t];
}

// ---------------- interp conv: one block per output point n ----------------
// in:  (N_in, CIN, 16)   [optionally bn-relu applied on load]
// out: (N2, COUT, 16)
template<int CIN, int COUT, bool AFFINE>
__global__ __launch_bounds__(256) void conv_kernel(
    const float* __restrict__ in, const int* __restrict__ idx,
    const float* __restrict__ Abuf, const float* __restrict__ W,
    const float* __restrict__ bias,
    const float* __restrict__ scale, const float* __restrict__ shift,
    float* __restrict__ out)
{
  constexpr int CB = CIN * BC;            // 48 or 512
  constexpr int TP = CIN * TC;            // 27 or 288
  constexpr int TPAD = (TP % 8 == 0) ? TP + 4 : ((TP + 3) & ~3); // 292 / 28
  constexpr int R = COUT / 16;            // 2 or 4

  __shared__ float As[81];
  __shared__ float Ts[16 * TPAD];

  int n = blockIdx.x;
  int tid = threadIdx.x;
  if (tid < 81) As[tid] = Abuf[(size_t)n*81 + tid];
  __syncthreads();

  // phase 2: taps[c][b][t] = sum_k feat[c,b,k] * A[k,t]
  for (int cb = tid; cb < CB; cb += 256){
    int b = cb & 15, c = cb >> 4;
    float sc = 0.f, sh = 0.f;
    if (AFFINE){ sc = scale[c]; sh = shift[c]; }
    float gv[KC];
    #pragma unroll
    for (int k = 0; k < KC; k++){
      int p = idx[n*KC + k];
      float v = in[(size_t)p*CB + cb];
      if (AFFINE) v = fmaxf(fmaf(v, sc, sh), 0.f);
      gv[k] = v;
    }
    #pragma unroll
    for (int t = 0; t < TC; t++){
      float s = 0.f;
      #pragma unroll
      for (int k = 0; k < KC; k++) s = fmaf(gv[k], As[k*TC + t], s);
      Ts[b*TPAD + c*TC + t] = s;
    }
  }
  __syncthreads();

  // phase 3: out[o][b] = bias[o] + sum_{i=(c,t)} taps[b][i] * W[o][i]
  int b = tid & 15, og = tid >> 4;        // og 0..15
  const float* tp = Ts + b*TPAD;
  float acc[R];
  #pragma unroll
  for (int r = 0; r < R; r++) acc[r] = bias[og + 16*r];

  if constexpr (TP % 4 == 0){
    #pragma unroll 2
    for (int i = 0; i < TP; i += 4){
      float4 tv = *(const float4*)(tp + i);
      #pragma unroll
      for (int r = 0; r < R; r++){
        float4 w = *(const float4*)(W + (size_t)(og + 16*r)*TP + i);
        acc[r] += tv.x*w.x + tv.y*w.y + tv.z*w.z + tv.w*w.w;
      }
    }
  } else {
    #pragma unroll
    for (int i = 0; i < TP; i++){
      float tv = tp[i];
      #pragma unroll
      for (int r = 0; r < R; r++) acc[r] = fmaf(tv, W[(size_t)(og + 16*r)*TP + i], acc[r]);
    }
  }

  float* outn = out + (size_t)n*COUT*BC;
  #pragma unroll
  for (int r = 0; r < R; r++) outn[(og + 16*r)*BC + b] = acc[r];
}

// ---------------- BN stats: deterministic two-stage ----------------
template<int C>
__global__ __launch_bounds__(256) void bn_stats_kernel(
    const float* __restrict__ h, float* __restrict__ part)
{
  const int S = 32;
  int c = blockIdx.x / S, s = blockIdx.x % S;
  const int chunk = (N2C * BC) / S;      // 6272
  int i0 = s * chunk;
  float sm = 0.f, sq = 0.f;
  for (int i = i0 + threadIdx.x; i < i0 + chunk; i += 256){
    int n = i >> 4, b = i & 15;
    float v = h[((size_t)n * C + c) * 16 + b];
    sm += v; sq = fmaf(v, v, sq);
  }
  #pragma unroll
  for (int off = 32; off > 0; off >>= 1){
    sm += __shfl_down(sm, off);
    sq += __shfl_down(sq, off);
  }
  __shared__ float red[8];
  int wid = threadIdx.x >> 6, lane = threadIdx.x & 63;
  if (lane == 0){ red[wid] = sm; red[4 + wid] = sq; }
  __syncthreads();
  if (threadIdx.x == 0){
    part[c*32 + s]        = red[0]+red[1]+red[2]+red[3];
    part[2048 + c*32 + s] = red[4]+red[5]+red[6]+red[7];
  }
}

__global__ void bn_finalize_kernel(
    const float* __restrict__ part, const float* __restrict__ g,
    const float* __restrict__ bb, float* __restrict__ scale,
    float* __restrict__ shift, int C, float invN)
{
  int c = threadIdx.x;
  if (c >= C) return;
  float sm = 0.f, sq = 0.f;
  for (int s = 0; s < 32; s++){ sm += part[c*32 + s]; sq += part[2048 + c*32 + s]; }
  float mean = sm * invN;
  float var  = fmaxf(sq * invN - mean*mean, 0.f);
  float sc = g[c] * rsqrtf(var + 1e-5f);
  scale[c] = sc;
  shift[c] = bb[c] - mean * sc;
}

// ---------------- BN3 + relu + max-pool + transpose to (B,64,N3) ----------------
__global__ __launch_bounds__(256) void pool_kernel(
    const float* __restrict__ h3, const int* __restrict__ pidx,
    const float* __restrict__ scale, const float* __restrict__ shift,
    float* __restrict__ out)
{
  __shared__ float P[16][1024];
  int m0 = blockIdx.x * 16;
  int tid = threadIdx.x;
  for (int mi = 0; mi < 16; mi++){
    int m = m0 + mi;
    int p0 = pidx[m*4+0], p1 = pidx[m*4+1], p2 = pidx[m*4+2], p3 = pidx[m*4+3];
    #pragma unroll
    for (int q = 0; q < 4; q++){
      int ob = tid + q*256;
      int o = ob >> 4;
      float sc = scale[o], sh = shift[o];
      float v0 = fmaf(h3[(size_t)p0*1024 + ob], sc, sh);
      float v1 = fmaf(h3[(size_t)p1*1024 + ob], sc, sh);
      float v2 = fmaf(h3[(size_t)p2*1024 + ob], sc, sh);
      float v3 = fmaf(h3[(size_t)p3*1024 + ob], sc, sh);
      P[mi][ob] = fmaxf(fmaxf(fmaxf(v0,v1), fmaxf(v2,v3)), 0.f);
    }
  }
  __syncthreads();
  int b = tid & 15, oo = tid >> 4;
  #pragma unroll
  for (int w = 0; w < 4; w++){
    int o = oo + 16*w;
    int q = b*64 + o;                     // out row (b*64+o)
    int ob = o*16 + b;
    float* dst = out + (size_t)q*N3C + m0;
    #pragma unroll
    for (int mi = 0; mi < 16; mi++) dst[mi] = P[mi][ob];
  }
}

// ---------------- launch ----------------
extern "C" void kernel_launch(void* const* d_in, const int* in_sizes, int n_in,
                              void* d_out, int out_size, void* d_ws, size_t ws_size,
                              hipStream_t stream)
{
  const float* x    = (const float*)d_in[0];
  const float* l1   = (const float*)d_in[1];
  const float* l2   = (const float*)d_in[2];
  const int* knn1   = (const int*)d_in[4];
  const int* knn2   = (const int*)d_in[5];
  const int* knn3   = (const int*)d_in[6];
  const int* pidx   = (const int*)d_in[7];

  const float* c1_w1 = (const float*)d_in[8];
  const float* c1_b1 = (const float*)d_in[9];
  const float* c1_w2 = (const float*)d_in[10];
  const float* c1_b2 = (const float*)d_in[11];
  const float* c1_k  = (const float*)d_in[12];
  const float* c1_bs = (const float*)d_in[13];
  const float* c2_w1 = (const float*)d_in[14];
  const float* c2_b1 = (const float*)d_in[15];
  const float* c2_w2 = (const float*)d_in[16];
  const float* c2_b2 = (const float*)d_in[17];
  const float* c2_k  = (const float*)d_in[18];
  const float* c2_bs = (const float*)d_in[19];
  const float* c3_w1 = (const float*)d_in[20];
  const float* c3_b1 = (const float*)d_in[21];
  const float* c3_w2 = (const float*)d_in[22];
  const float* c3_b2 = (const float*)d_in[23];
  const float* c3_k  = (const float*)d_in[24];
  const float* c3_bs = (const float*)d_in[25];
  const float* bn1_g = (const float*)d_in[26];
  const float* bn1_b = (const float*)d_in[27];
  const float* bn2_g = (const float*)d_in[28];
  const float* bn2_b = (const float*)d_in[29];
  const float* bn3_g = (const float*)d_in[30];
  const float* bn3_b = (const float*)d_in[31];

  float* ws = (float*)d_ws;
  const size_t OFF_XT = 0;
  const size_t OFF_H1 = OFF_XT + (size_t)N1C * 48;
  const size_t OFF_H2 = OFF_H1 + (size_t)N2C * 512;
  const size_t OFF_H3 = OFF_H2 + (size_t)N2C * 512;
  const size_t OFF_ST = OFF_H3 + (size_t)N2C * 1024;

  float* xT  = ws + OFF_XT;
  float* h1  = ws + OFF_H1;
  float* h2  = ws + OFF_H2;
  float* h3  = ws + OFF_H3;
  float* A12 = ws + OFF_H3;   // A1/A2 live in (not-yet-used) h3 region
  float* A3  = ws + OFF_XT;   // A3 lives in dead xT region
  float* part = ws + OFF_ST;  // 4096 floats of partials
  float* sc1 = part + 4096;  float* sh1 = sc1 + 32;
  float* sc2 = sh1 + 32;     float* sh2 = sc2 + 32;
  float* sc3 = sh2 + 32;     float* sh3 = sc3 + 64;

  const float invN = 1.0f / (float)(N2C * BC);
  const int ablocks = (N2C * KC + 255) / 256;

  transpose_x_kernel<<<N1C/64, 256, 0, stream>>>(x, xT);

  // conv1
  compute_A_kernel<<<ablocks, 256, 0, stream>>>(l1, l2, knn1, c1_w1, c1_b1, c1_w2, c1_b2, A12);
  conv_kernel<3, 32, false><<<N2C, 256, 0, stream>>>(xT, knn1, A12, c1_k, c1_bs, nullptr, nullptr, h1);
  bn_stats_kernel<32><<<32*32, 256, 0, stream>>>(h1, part);
  bn_finalize_kernel<<<1, 64, 0, stream>>>(part, bn1_g, bn1_b, sc1, sh1, 32, invN);

  // conv2
  compute_A_kernel<<<ablocks, 256, 0, stream>>>(l2, l2, knn2, c2_w1, c2_b1, c2_w2, c2_b2, A12);
  conv_kernel<32, 32, true><<<N2C, 256, 0, stream>>>(h1, knn2, A12, c2_k, c2_bs, sc1, sh1, h2);
  bn_stats_kernel<32><<<32*32, 256, 0, stream>>>(h2, part);
  bn_finalize_kernel<<<1, 64, 0, stream>>>(part, bn2_g, bn2_b, sc2, sh2, 32, invN);

  // conv3
  compute_A_kernel<<<ablocks, 256, 0, stream>>>(l2, l2, knn3, c3_w1, c3_b1, c3_w2, c3_b2, A3);
  conv_kernel<32, 64, true><<<N2C, 256, 0, stream>>>(h2, knn3, A3, c3_k, c3_bs, sc2, sh2, h3);
  bn_stats_kernel<64><<<64*32, 256, 0, stream>>>(h3, part);
  bn_finalize_kernel<<<1, 64, 0, stream>>>(part, bn3_g, bn3_b, sc3, sh3, 64, invN);

  // bn3 + relu + pool + transpose
  pool_kernel<<<N3C/16, 256, 0, stream>>>(h3, pidx, sc3, sh3, (float*)d_out);
}

// Round 2
// 230.268 us; speedup vs baseline: 3.1841x; 3.1841x over previous
//
#include <hip/hip_runtime.h>
#include <hip/hip_bf16.h>
#include <cfloat>

#define N1C 50176
#define N2C 12544
#define N3C 3136
#define BC  16
#define KC  9
#define TC  9

typedef __attribute__((ext_vector_type(8))) short short8v;
typedef __attribute__((ext_vector_type(4))) float f32x4;

// ---------------- transpose x: (B,3,N1) -> xT (N1, 3, 16) ----------------
__global__ __launch_bounds__(256) void transpose_x_kernel(
    const float* __restrict__ x, float* __restrict__ xT)
{
  __shared__ float tile[48][65];
  int n0 = blockIdx.x * 64;
  int tid = threadIdx.x;
  int i = tid & 63;
  for (int rr = tid >> 6; rr < 48; rr += 4){
    int b = rr / 3, c = rr % 3;
    tile[c*16 + b][i] = x[(size_t)rr * N1C + n0 + i];
  }
  __syncthreads();
  for (int j = tid; j < 48*64; j += 256){
    int ii = j / 48, cb = j % 48;
    xT[(size_t)n0 * 48 + j] = tile[cb][ii];
  }
}

// ---------------- A[n,k,t] = (relu(off @ w1 + b1) @ w2 + b2) ----------------
__global__ __launch_bounds__(256) void compute_A_kernel(
    const float* __restrict__ pos_in, const float* __restrict__ pos_out,
    const int* __restrict__ idx,
    const float* __restrict__ w1, const float* __restrict__ b1,
    const float* __restrict__ w2, const float* __restrict__ b2,
    float* __restrict__ Abuf)
{
  int g = blockIdx.x * 256 + threadIdx.x;
  if (g >= N2C * KC) return;
  int n = g / KC;
  int p = idx[g];
  float o0 = pos_in[2*p]   - pos_out[2*n];
  float o1 = pos_in[2*p+1] - pos_out[2*n+1];
  float A[TC];
  #pragma unroll
  for (int t = 0; t < TC; t++) A[t] = b2[t];
  #pragma unroll
  for (int j = 0; j < 16; j++){
    float h = fmaxf(fmaf(o0, w1[j], fmaf(o1, w1[16+j], b1[j])), 0.f);
    #pragma unroll
    for (int t = 0; t < TC; t++) A[t] = fmaf(h, w2[j*TC + t], A[t]);
  }
  #pragma unroll
  for (int t = 0; t < TC; t++) Abuf[(size_t)g*TC + t] = A[t];
}

// ---------------- W (o,c,t) f32 -> Wb[o][k] bf16, k zero-padded to KW --------
__global__ __launch_bounds__(256) void wcvt_kernel(
    const float* __restrict__ W, __hip_bfloat16* __restrict__ Wb,
    int total, int K, int KW)
{
  int i = blockIdx.x * 256 + threadIdx.x;
  if (i >= total) return;
  int o = i / KW, k = i % KW;
  Wb[i] = __float2bfloat16(k < K ? W[o*K + k] : 0.f);
}

// ---------------- interp conv with MFMA phase-3 ----------------
// in: (N_in, CIN, 16) f32; out: (N2, COUT, 16) f32
// taps staged in LDS as bf16 [b][k] (k = c*9+t contiguous); W bf16 [o][k].
template<int CIN, int COUT, int NPB, bool AFFINE>
__global__ __launch_bounds__(256) void conv_mfma_kernel(
    const float* __restrict__ in, const int* __restrict__ idx,
    const float* __restrict__ Abuf, const __hip_bfloat16* __restrict__ Wb,
    const float* __restrict__ bias,
    const float* __restrict__ scale, const float* __restrict__ shift,
    float* __restrict__ out)
{
  constexpr int K    = CIN * 9;            // 27 or 288
  constexpr int KW   = (K < 32) ? 32 : K;  // W row stride (bf16), mult of 32
  constexpr int KROW = (K < 32) ? 40 : 296;// taps row stride (bf16): 16B-mult, 2-way banks
  constexpr int CHUNKS = KW / 32;
  constexpr int CB   = CIN * 16;
  constexpr int OT   = COUT / 16;          // o-tiles per point

  __shared__ alignas(16) __hip_bfloat16 Tb[NPB * 16 * KROW];
  __shared__ float As[NPB * 81];
  __shared__ int   Ip[NPB * 9];

  int n0 = blockIdx.x * NPB;
  int tid = threadIdx.x;
  for (int i = tid; i < NPB*81; i += 256) As[i] = Abuf[(size_t)n0*81 + i];
  if (tid < NPB*9) Ip[tid] = idx[n0*9 + tid];
  if (K < 32){
    for (int i = tid; i < NPB*16*KROW/2; i += 256) ((unsigned*)Tb)[i] = 0u;
  }
  __syncthreads();

  // phase 2: gather + taps (f32), store bf16
  for (int cb = tid; cb < NPB*CB; cb += 256){
    int ni = cb / CB, rem = cb % CB, c = rem >> 4, b = rem & 15;
    float sc = 1.f, sh = 0.f;
    if (AFFINE){ sc = scale[c]; sh = shift[c]; }
    const float* As_n = As + ni*81;
    const int*   ip   = Ip + ni*9;
    float gv[KC];
    #pragma unroll
    for (int k = 0; k < KC; k++){
      float v = in[(size_t)ip[k]*CB + rem];
      gv[k] = AFFINE ? fmaxf(fmaf(v, sc, sh), 0.f) : v;
    }
    __hip_bfloat16* trow = Tb + (ni*16 + b)*KROW + c*9;
    #pragma unroll
    for (int t = 0; t < TC; t++){
      float s = 0.f;
      #pragma unroll
      for (int k = 0; k < KC; k++) s = fmaf(gv[k], As_n[k*9 + t], s);
      trow[t] = __float2bfloat16(s);
    }
  }
  __syncthreads();

  // phase 3: per wave, D(16x16) = W_tile(16xK) . taps(Kx16) via MFMA
  int w = tid >> 6, l = tid & 63;
  int ni = w / OT, ot = w % OT;
  int lr = l & 15, lg = l >> 4;
  f32x4 acc;
  #pragma unroll
  for (int r = 0; r < 4; r++) acc[r] = bias[16*ot + lg*4 + r];

  const short8v* ap = (const short8v*)(Wb + (size_t)(16*ot + lr)*KW + lg*8);
  const short8v* bp = (const short8v*)(Tb + (ni*16 + lr)*KROW + lg*8);
  #pragma unroll
  for (int kk = 0; kk < CHUNKS; kk++){
    short8v a = ap[kk*4];
    short8v b = bp[kk*4];
    acc = __builtin_amdgcn_mfma_f32_16x16x32_bf16(a, b, acc, 0, 0, 0);
  }
  float* outn = out + (size_t)(n0 + ni)*COUT*16;
  #pragma unroll
  for (int r = 0; r < 4; r++) outn[(16*ot + lg*4 + r)*16 + lr] = acc[r];
}

// ---------------- BN stats: deterministic two-stage ----------------
template<int C>
__global__ __launch_bounds__(256) void bn_stats_kernel(
    const float* __restrict__ h, float* __restrict__ part)
{
  const int S = 32;
  int c = blockIdx.x / S, s = blockIdx.x % S;
  const int chunk = (N2C * BC) / S;
  int i0 = s * chunk;
  float sm = 0.f, sq = 0.f;
  for (int i = i0 + threadIdx.x; i < i0 + chunk; i += 256){
    int n = i >> 4, b = i & 15;
    float v = h[((size_t)n * C + c) * 16 + b];
    sm += v; sq = fmaf(v, v, sq);
  }
  #pragma unroll
  for (int off = 32; off > 0; off >>= 1){
    sm += __shfl_down(sm, off);
    sq += __shfl_down(sq, off);
  }
  __shared__ float red[8];
  int wid = threadIdx.x >> 6, lane = threadIdx.x & 63;
  if (lane == 0){ red[wid] = sm; red[4 + wid] = sq; }
  __syncthreads();
  if (threadIdx.x == 0){
    part[c*32 + s]        = red[0]+red[1]+red[2]+red[3];
    part[2048 + c*32 + s] = red[4]+red[5]+red[6]+red[7];
  }
}

__global__ void bn_finalize_kernel(
    const float* __restrict__ part, const float* __restrict__ g,
    const float* __restrict__ bb, float* __restrict__ scale,
    float* __restrict__ shift, int C, float invN)
{
  int c = threadIdx.x;
  if (c >= C) return;
  float sm = 0.f, sq = 0.f;
  for (int s = 0; s < 32; s++){ sm += part[c*32 + s]; sq += part[2048 + c*32 + s]; }
  float mean = sm * invN;
  float var  = fmaxf(sq * invN - mean*mean, 0.f);
  float sc = g[c] * rsqrtf(var + 1e-5f);
  scale[c] = sc;
  shift[c] = bb[c] - mean * sc;
}

// ---------------- BN3 + relu + max-pool + transpose to (B,64,N3) ----------------
__global__ __launch_bounds__(256) void pool_kernel(
    const float* __restrict__ h3, const int* __restrict__ pidx,
    const float* __restrict__ scale, const float* __restrict__ shift,
    float* __restrict__ out)
{
  __shared__ float P[16][1024];
  int m0 = blockIdx.x * 16;
  int tid = threadIdx.x;
  for (int mi = 0; mi < 16; mi++){
    int m = m0 + mi;
    int p0 = pidx[m*4+0], p1 = pidx[m*4+1], p2 = pidx[m*4+2], p3 = pidx[m*4+3];
    #pragma unroll
    for (int q = 0; q < 4; q++){
      int ob = tid + q*256;
      int o = ob >> 4;
      float sc = scale[o], sh = shift[o];
      float v0 = fmaf(h3[(size_t)p0*1024 + ob], sc, sh);
      float v1 = fmaf(h3[(size_t)p1*1024 + ob], sc, sh);
      float v2 = fmaf(h3[(size_t)p2*1024 + ob], sc, sh);
      float v3 = fmaf(h3[(size_t)p3*1024 + ob], sc, sh);
      P[mi][ob] = fmaxf(fmaxf(fmaxf(v0,v1), fmaxf(v2,v3)), 0.f);
    }
  }
  __syncthreads();
  int b = tid & 15, oo = tid >> 4;
  #pragma unroll
  for (int w = 0; w < 4; w++){
    int o = oo + 16*w;
    int q = b*64 + o;
    int ob = o*16 + b;
    float* dst = out + (size_t)q*N3C + m0;
    #pragma unroll
    for (int mi = 0; mi < 16; mi++) dst[mi] = P[mi][ob];
  }
}

// ---------------- launch ----------------
extern "C" void kernel_launch(void* const* d_in, const int* in_sizes, int n_in,
                              void* d_out, int out_size, void* d_ws, size_t ws_size,
                              hipStream_t stream)
{
  const float* x    = (const float*)d_in[0];
  const float* l1   = (const float*)d_in[1];
  const float* l2   = (const float*)d_in[2];
  const int* knn1   = (const int*)d_in[4];
  const int* knn2   = (const int*)d_in[5];
  const int* knn3   = (const int*)d_in[6];
  const int* pidx   = (const int*)d_in[7];

  const float* c1_w1 = (const float*)d_in[8];
  const float* c1_b1 = (const float*)d_in[9];
  const float* c1_w2 = (const float*)d_in[10];
  const float* c1_b2 = (const float*)d_in[11];
  const float* c1_k  = (const float*)d_in[12];
  const float* c1_bs = (const float*)d_in[13];
  const float* c2_w1 = (const float*)d_in[14];
  const float* c2_b1 = (const float*)d_in[15];
  const float* c2_w2 = (const float*)d_in[16];
  const float* c2_b2 = (const float*)d_in[17];
  const float* c2_k  = (const float*)d_in[18];
  const float* c2_bs = (const float*)d_in[19];
  const float* c3_w1 = (const float*)d_in[20];
  const float* c3_b1 = (const float*)d_in[21];
  const float* c3_w2 = (const float*)d_in[22];
  const float* c3_b2 = (const float*)d_in[23];
  const float* c3_k  = (const float*)d_in[24];
  const float* c3_bs = (const float*)d_in[25];
  const float* bn1_g = (const float*)d_in[26];
  const float* bn1_b = (const float*)d_in[27];
  const float* bn2_g = (const float*)d_in[28];
  const float* bn2_b = (const float*)d_in[29];
  const float* bn3_g = (const float*)d_in[30];
  const float* bn3_b = (const float*)d_in[31];

  float* ws = (float*)d_ws;
  const size_t OFF_XT = 0;
  const size_t OFF_H1 = OFF_XT + (size_t)N1C * 48;
  const size_t OFF_H2 = OFF_H1 + (size_t)N2C * 512;
  const size_t OFF_H3 = OFF_H2 + (size_t)N2C * 512;
  const size_t OFF_ST = OFF_H3 + (size_t)N2C * 1024;

  float* xT  = ws + OFF_XT;
  float* h1  = ws + OFF_H1;
  float* h2  = ws + OFF_H2;
  float* h3  = ws + OFF_H3;
  float* A12 = ws + OFF_H3;            // dead until conv3 writes h3
  float* A3  = ws + OFF_XT;            // xT dead after conv1
  float* part = ws + OFF_ST;
  float* sc1 = part + 4096;  float* sh1 = sc1 + 32;
  float* sc2 = sh1 + 32;     float* sh2 = sc2 + 32;
  float* sc3 = sh2 + 32;     float* sh3 = sc3 + 64;
  // bf16 weights, parked in currently-dead regions
  __hip_bfloat16* wb1 = (__hip_bfloat16*)(ws + OFF_H3 + 2000000);  // h3 dead till conv3
  __hip_bfloat16* wb2 = (__hip_bfloat16*)(ws + OFF_H3 + 2001024);
  __hip_bfloat16* wb3 = (__hip_bfloat16*)(ws + OFF_XT + 2000000);  // xT dead after conv1

  const float invN = 1.0f / (float)(N2C * BC);
  const int ablocks = (N2C * KC + 255) / 256;

  transpose_x_kernel<<<N1C/64, 256, 0, stream>>>(x, xT);
  wcvt_kernel<<<(32*32 + 255)/256, 256, 0, stream>>>(c1_k, wb1, 32*32, 27, 32);
  wcvt_kernel<<<(32*288 + 255)/256, 256, 0, stream>>>(c2_k, wb2, 32*288, 288, 288);

  // conv1
  compute_A_kernel<<<ablocks, 256, 0, stream>>>(l1, l2, knn1, c1_w1, c1_b1, c1_w2, c1_b2, A12);
  conv_mfma_kernel<3, 32, 2, false><<<N2C/2, 256, 0, stream>>>(xT, knn1, A12, wb1, c1_bs, nullptr, nullptr, h1);
  bn_stats_kernel<32><<<32*32, 256, 0, stream>>>(h1, part);
  bn_finalize_kernel<<<1, 64, 0, stream>>>(part, bn1_g, bn1_b, sc1, sh1, 32, invN);

  // conv2
  compute_A_kernel<<<ablocks, 256, 0, stream>>>(l2, l2, knn2, c2_w1, c2_b1, c2_w2, c2_b2, A12);
  conv_mfma_kernel<32, 32, 2, true><<<N2C/2, 256, 0, stream>>>(h1, knn2, A12, wb2, c2_bs, sc1, sh1, h2);
  bn_stats_kernel<32><<<32*32, 256, 0, stream>>>(h2, part);
  bn_finalize_kernel<<<1, 64, 0, stream>>>(part, bn2_g, bn2_b, sc2, sh2, 32, invN);

  // conv3 (xT is dead now: wb3 + A3 live there)
  wcvt_kernel<<<(64*288 + 255)/256, 256, 0, stream>>>(c3_k, wb3, 64*288, 288, 288);
  compute_A_kernel<<<ablocks, 256, 0, stream>>>(l2, l2, knn3, c3_w1, c3_b1, c3_w2, c3_b2, A3);
  conv_mfma_kernel<32, 64, 1, true><<<N2C, 256, 0, stream>>>(h2, knn3, A3, wb3, c3_bs, sc2, sh2, h3);
  bn_stats_kernel<64><<<64*32, 256, 0, stream>>>(h3, part);
  bn_finalize_kernel<<<1, 64, 0, stream>>>(part, bn3_g, bn3_b, sc3, sh3, 64, invN);

  pool_kernel<<<N3C/16, 256, 0, stream>>>(h3, pidx, sc3, sh3, (float*)d_out);
}

// Round 3
// 210.973 us; speedup vs baseline: 3.4753x; 1.0915x over previous
//
#include <hip/hip_runtime.h>
#include <hip/hip_bf16.h>
#include <cfloat>

#define N1C 50176
#define N2C 12544
#define N3C 3136

typedef __attribute__((ext_vector_type(8))) short short8v;
typedef __attribute__((ext_vector_type(4))) float f32x4;

static __device__ __forceinline__ unsigned short f2bf(float f){
  __hip_bfloat16 h = __float2bfloat16(f);
  return *reinterpret_cast<unsigned short*>(&h);
}
static __device__ __forceinline__ float bflo(unsigned v){   // low 16 bits -> f32
  return __uint_as_float(v << 16);
}
static __device__ __forceinline__ float bfhi(unsigned v){   // high 16 bits -> f32
  return __uint_as_float(v & 0xFFFF0000u);
}
static __device__ __forceinline__ float bf2f(unsigned short u){
  return __uint_as_float(((unsigned)u) << 16);
}

// ---------------- transpose x: (16,3,N1) f32 -> xTb (N1, 16, 4) bf16, c=3 pad 0 ----
__global__ __launch_bounds__(256) void transpose_x_kernel(
    const float* __restrict__ x, unsigned short* __restrict__ xTb)
{
  __shared__ float tile[48][65];
  int n0 = blockIdx.x * 64;
  int tid = threadIdx.x;
  int i = tid & 63;
  for (int rr = tid >> 6; rr < 48; rr += 4)
    tile[rr][i] = x[(size_t)rr * N1C + n0 + i];
  __syncthreads();
  for (int j = tid; j < 64*64; j += 256){
    int ii = j >> 6, bc = j & 63, b = bc >> 2, c = bc & 3;
    float v = (c < 3) ? tile[b*3 + c][ii] : 0.f;
    xTb[(size_t)n0 * 64 + j] = f2bf(v);
  }
}

// ---------------- A[n,k,t] = (relu(off @ w1 + b1) @ w2 + b2) ----------------
__global__ __launch_bounds__(256) void compute_A_kernel(
    const float* __restrict__ pos_in, const float* __restrict__ pos_out,
    const int* __restrict__ idx,
    const float* __restrict__ w1, const float* __restrict__ b1,
    const float* __restrict__ w2, const float* __restrict__ b2,
    float* __restrict__ Abuf)
{
  int g = blockIdx.x * 256 + threadIdx.x;
  if (g >= N2C * 9) return;
  int n = g / 9;
  int p = idx[g];
  float o0 = pos_in[2*p]   - pos_out[2*n];
  float o1 = pos_in[2*p+1] - pos_out[2*n+1];
  float A[9];
  #pragma unroll
  for (int t = 0; t < 9; t++) A[t] = b2[t];
  #pragma unroll
  for (int j = 0; j < 16; j++){
    float h = fmaxf(fmaf(o0, w1[j], fmaf(o1, w1[16+j], b1[j])), 0.f);
    #pragma unroll
    for (int t = 0; t < 9; t++) A[t] = fmaf(h, w2[j*9 + t], A[t]);
  }
  #pragma unroll
  for (int t = 0; t < 9; t++) Abuf[(size_t)g*9 + t] = A[t];
}

// ---------------- W (o,k) f32 -> Wb[o][k] bf16, zero-padded to KW --------
__global__ __launch_bounds__(256) void wcvt_kernel(
    const float* __restrict__ W, unsigned short* __restrict__ Wb,
    int total, int K, int KW)
{
  int i = blockIdx.x * 256 + threadIdx.x;
  if (i >= total) return;
  int o = i / KW, k = i % KW;
  Wb[i] = f2bf(k < K ? W[o*K + k] : 0.f);
}

// ---------------- interp conv, bf16 in/out, fused BN-stats partials ----------
// in : (N_in, 16, CINP) bf16    out : (N2, 16, COUT) bf16
template<int CIN, int CINP, int COUT, int NPB, bool AFFINE>
__global__ __launch_bounds__(256) void conv_mfma_kernel(
    const unsigned short* __restrict__ in, const int* __restrict__ idx,
    const float* __restrict__ Abuf, const unsigned short* __restrict__ Wb,
    const float* __restrict__ bias,
    const float* __restrict__ scale, const float* __restrict__ shift,
    unsigned short* __restrict__ out, float* __restrict__ gpart)
{
  constexpr int K    = CIN * 9;
  constexpr int KW   = (K < 32) ? 32 : K;
  constexpr int KROW = (K < 32) ? 48 : 296;   // shorts; 16B-multiple row stride
  constexpr int CHUNKS = KW / 32;
  constexpr int OT   = COUT / 16;
  constexpr int HP   = CINP / 2;              // bfloat162 pairs per b
  constexpr int PPT  = 16 * HP;               // threads per point

  __shared__ alignas(16) unsigned short Tb[NPB * 16 * KROW];
  __shared__ float As[NPB * 81];
  __shared__ int   Ip[NPB * 9];
  __shared__ float Sw[4 * COUT];
  __shared__ float Sq[4 * COUT];

  int n0 = blockIdx.x * NPB;
  int tid = threadIdx.x;
  for (int i = tid; i < NPB*81; i += 256) As[i] = Abuf[(size_t)n0*81 + i];
  if (tid < NPB*9) Ip[tid] = idx[n0*9 + tid];
  for (int i = tid; i < 4*COUT; i += 256){ Sw[i] = 0.f; Sq[i] = 0.f; }
  __syncthreads();

  // ---- phase 2: gather (bf16 pairs) + BN/relu + 9x9 taps -> Tb bf16 ----
  for (int u = tid; u < NPB*PPT; u += 256){
    int ni = u / PPT, loc = u % PPT;
    int b = loc / HP, c2 = loc % HP;
    const float* As_n = As + ni*81;
    const int*   ip   = Ip + ni*9;
    float scx=1.f, shx=0.f, scy=1.f, shy=0.f;
    if (AFFINE){
      scx = scale[2*c2];   shx = shift[2*c2];
      scy = scale[2*c2+1]; shy = shift[2*c2+1];
    }
    float fx[9], fy[9];
    #pragma unroll
    for (int k = 0; k < 9; k++){
      unsigned v = *(const unsigned*)(in + ((size_t)ip[k]*16 + b)*CINP + 2*c2);
      float x0 = bflo(v), y0 = bfhi(v);
      if (AFFINE){
        x0 = fmaxf(fmaf(x0, scx, shx), 0.f);
        y0 = fmaxf(fmaf(y0, scy, shy), 0.f);
      }
      fx[k] = x0; fy[k] = y0;
    }
    unsigned short e[18];
    #pragma unroll
    for (int t = 0; t < 9; t++){
      float s0 = 0.f, s1 = 0.f;
      #pragma unroll
      for (int k = 0; k < 9; k++){
        float a = As_n[k*9 + t];
        s0 = fmaf(fx[k], a, s0);
        s1 = fmaf(fy[k], a, s1);
      }
      e[t] = f2bf(s0); e[9+t] = f2bf(s1);
    }
    unsigned* dst = (unsigned*)(Tb + (ni*16 + b)*KROW + 18*c2);
    #pragma unroll
    for (int j = 0; j < 9; j++) dst[j] = (unsigned)e[2*j] | ((unsigned)e[2*j+1] << 16);
  }
  __syncthreads();

  // ---- phase 3: MFMA D(16x16) = W(16xK) . taps(Kx16), packed bf16 store ----
  int w = tid >> 6, l = tid & 63, lr = l & 15, lg = l >> 4;
  float smr[4] = {0,0,0,0}, sqr[4] = {0,0,0,0};
  int oBase = 0;
  for (int wi = w; wi < NPB*OT; wi += 4){
    int ni = wi / OT, ot = wi % OT;     // ot is constant across this wave's iters
    oBase = 16*ot + 4*lg;
    f32x4 acc;
    #pragma unroll
    for (int r = 0; r < 4; r++) acc[r] = bias[oBase + r];
    const short8v* ap = (const short8v*)(Wb + (size_t)(16*ot + lr)*KW) + lg;
    const short8v* bp = (const short8v*)(Tb + (ni*16 + lr)*KROW) + lg;
    #pragma unroll
    for (int kk = 0; kk < CHUNKS; kk++)
      acc = __builtin_amdgcn_mfma_f32_16x16x32_bf16(ap[kk*4], bp[kk*4], acc, 0, 0, 0);
    ushort4 o4;
    o4.x = f2bf(acc[0]); o4.y = f2bf(acc[1]); o4.z = f2bf(acc[2]); o4.w = f2bf(acc[3]);
    *(ushort4*)(out + ((size_t)(n0 + ni)*16 + lr)*COUT + oBase) = o4;
    #pragma unroll
    for (int r = 0; r < 4; r++){
      smr[r] += acc[r];
      sqr[r] = fmaf(acc[r], acc[r], sqr[r]);
    }
  }
  #pragma unroll
  for (int m = 1; m < 16; m <<= 1){
    #pragma unroll
    for (int r = 0; r < 4; r++){
      smr[r] += __shfl_xor(smr[r], m);
      sqr[r] += __shfl_xor(sqr[r], m);
    }
  }
  if (lr == 0){
    #pragma unroll
    for (int r = 0; r < 4; r++){
      Sw[w*COUT + oBase + r] = smr[r];
      Sq[w*COUT + oBase + r] = sqr[r];
    }
  }
  __syncthreads();
  for (int o = tid; o < COUT; o += 256){
    float sm = Sw[o] + Sw[COUT + o] + Sw[2*COUT + o] + Sw[3*COUT + o];
    float sq = Sq[o] + Sq[COUT + o] + Sq[2*COUT + o] + Sq[3*COUT + o];
    gpart[(size_t)blockIdx.x * 2*COUT + o] = sm;
    gpart[(size_t)blockIdx.x * 2*COUT + COUT + o] = sq;
  }
}

// ---------------- finalize BN: one block per channel ----------------
__global__ __launch_bounds__(256) void bn_finalize_kernel(
    const float* __restrict__ gpart, int NB, int C,
    const float* __restrict__ g, const float* __restrict__ bb,
    float* __restrict__ sc, float* __restrict__ sh, float invN)
{
  int c = blockIdx.x;
  float sm = 0.f, sq = 0.f;
  for (int i = threadIdx.x; i < NB; i += 256){
    sm += gpart[(size_t)i*2*C + c];
    sq += gpart[(size_t)i*2*C + C + c];
  }
  #pragma unroll
  for (int off = 32; off > 0; off >>= 1){
    sm += __shfl_down(sm, off);
    sq += __shfl_down(sq, off);
  }
  __shared__ float rs[8];
  int wd = threadIdx.x >> 6, ln = threadIdx.x & 63;
  if (ln == 0){ rs[wd] = sm; rs[4+wd] = sq; }
  __syncthreads();
  if (threadIdx.x == 0){
    float S = rs[0]+rs[1]+rs[2]+rs[3], Q = rs[4]+rs[5]+rs[6]+rs[7];
    float mean = S * invN;
    float var  = fmaxf(Q * invN - mean*mean, 0.f);
    float s = g[c] * rsqrtf(var + 1e-5f);
    sc[c] = s;
    sh[c] = bb[c] - mean * s;
  }
}

// ------------- BN3 + relu + max-pool + write (16,64,N3) f32 -------------
__global__ __launch_bounds__(256) void pool_kernel(
    const unsigned short* __restrict__ h3, const int* __restrict__ pidx,
    const float* __restrict__ sc, const float* __restrict__ sh,
    float* __restrict__ out)
{
  __shared__ float P[16][1024];
  int m0 = blockIdx.x * 16;
  int tid = threadIdx.x;
  for (int mi = 0; mi < 16; mi++){
    int m = m0 + mi;
    int p0 = pidx[m*4+0], p1 = pidx[m*4+1], p2 = pidx[m*4+2], p3 = pidx[m*4+3];
    #pragma unroll
    for (int q = 0; q < 4; q++){
      int bo = tid + q*256;
      int o = bo & 63;
      float s = sc[o], h = sh[o];
      float v0 = fmaf(bf2f(h3[(size_t)p0*1024 + bo]), s, h);
      float v1 = fmaf(bf2f(h3[(size_t)p1*1024 + bo]), s, h);
      float v2 = fmaf(bf2f(h3[(size_t)p2*1024 + bo]), s, h);
      float v3 = fmaf(bf2f(h3[(size_t)p3*1024 + bo]), s, h);
      P[mi][bo] = fmaxf(fmaxf(fmaxf(v0,v1), fmaxf(v2,v3)), 0.f);
    }
  }
  __syncthreads();
  #pragma unroll
  for (int w = 0; w < 4; w++){
    int r = tid + w*256;
    float* dst = out + (size_t)r*N3C + m0;
    #pragma unroll
    for (int mi = 0; mi < 16; mi++) dst[mi] = P[mi][r];
  }
}

// ---------------- launch ----------------
extern "C" void kernel_launch(void* const* d_in, const int* in_sizes, int n_in,
                              void* d_out, int out_size, void* d_ws, size_t ws_size,
                              hipStream_t stream)
{
  const float* x    = (const float*)d_in[0];
  const float* l1   = (const float*)d_in[1];
  const float* l2   = (const float*)d_in[2];
  const int* knn1   = (const int*)d_in[4];
  const int* knn2   = (const int*)d_in[5];
  const int* knn3   = (const int*)d_in[6];
  const int* pidx   = (const int*)d_in[7];

  const float* c1_w1 = (const float*)d_in[8];
  const float* c1_b1 = (const float*)d_in[9];
  const float* c1_w2 = (const float*)d_in[10];
  const float* c1_b2 = (const float*)d_in[11];
  const float* c1_k  = (const float*)d_in[12];
  const float* c1_bs = (const float*)d_in[13];
  const float* c2_w1 = (const float*)d_in[14];
  const float* c2_b1 = (const float*)d_in[15];
  const float* c2_w2 = (const float*)d_in[16];
  const float* c2_b2 = (const float*)d_in[17];
  const float* c2_k  = (const float*)d_in[18];
  const float* c2_bs = (const float*)d_in[19];
  const float* c3_w1 = (const float*)d_in[20];
  const float* c3_b1 = (const float*)d_in[21];
  const float* c3_w2 = (const float*)d_in[22];
  const float* c3_b2 = (const float*)d_in[23];
  const float* c3_k  = (const float*)d_in[24];
  const float* c3_bs = (const float*)d_in[25];
  const float* bn1_g = (const float*)d_in[26];
  const float* bn1_b = (const float*)d_in[27];
  const float* bn2_g = (const float*)d_in[28];
  const float* bn2_b = (const float*)d_in[29];
  const float* bn3_g = (const float*)d_in[30];
  const float* bn3_b = (const float*)d_in[31];

  char* ws = (char*)d_ws;
  // byte offsets, all 16B-aligned
  unsigned short* xTb = (unsigned short*)(ws + 0);               //  6,422,528 B
  unsigned short* h1  = (unsigned short*)(ws + 6422528);         // 12,845,056 B
  unsigned short* h2  = (unsigned short*)(ws + 19267584);        // 12,845,056 B
  unsigned short* h3  = (unsigned short*)(ws + 32112640);        // 25,690,112 B
  float* Abuf         = (float*)(ws + 57802752);                 //  4,064,256 B
  float* gpart        = (float*)(ws + 61867008);                 //  3,211,264 B
  unsigned short* wb1 = (unsigned short*)(ws + 65078272);        //      2,048 B
  unsigned short* wb2 = (unsigned short*)(ws + 65081344);        //     18,432 B
  unsigned short* wb3 = (unsigned short*)(ws + 65099776);        //     36,864 B
  float* sc1 = (float*)(ws + 65137664); float* sh1 = sc1 + 32;
  float* sc2 = sh1 + 32;                float* sh2 = sc2 + 32;
  float* sc3 = sh2 + 32;                float* sh3 = sc3 + 64;

  const float invN = 1.0f / (float)(N2C * 16);
  const int ablocks = (N2C * 9 + 255) / 256;

  transpose_x_kernel<<<N1C/64, 256, 0, stream>>>(x, xTb);
  wcvt_kernel<<<(32*32 + 255)/256, 256, 0, stream>>>(c1_k, wb1, 32*32, 27, 32);
  wcvt_kernel<<<(32*288 + 255)/256, 256, 0, stream>>>(c2_k, wb2, 32*288, 288, 288);
  wcvt_kernel<<<(64*288 + 255)/256, 256, 0, stream>>>(c3_k, wb3, 64*288, 288, 288);

  // conv1: CIN=3 (stored CINP=4), COUT=32, 8 points/block
  compute_A_kernel<<<ablocks, 256, 0, stream>>>(l1, l2, knn1, c1_w1, c1_b1, c1_w2, c1_b2, Abuf);
  conv_mfma_kernel<3, 4, 32, 8, false><<<N2C/8, 256, 0, stream>>>(
      xTb, knn1, Abuf, wb1, c1_bs, nullptr, nullptr, h1, gpart);
  bn_finalize_kernel<<<32, 256, 0, stream>>>(gpart, N2C/8, 32, bn1_g, bn1_b, sc1, sh1, invN);

  // conv2
  compute_A_kernel<<<ablocks, 256, 0, stream>>>(l2, l2, knn2, c2_w1, c2_b1, c2_w2, c2_b2, Abuf);
  conv_mfma_kernel<32, 32, 32, 2, true><<<N2C/2, 256, 0, stream>>>(
      h1, knn2, Abuf, wb2, c2_bs, sc1, sh1, h2, gpart);
  bn_finalize_kernel<<<32, 256, 0, stream>>>(gpart, N2C/2, 32, bn2_g, bn2_b, sc2, sh2, invN);

  // conv3
  compute_A_kernel<<<ablocks, 256, 0, stream>>>(l2, l2, knn3, c3_w1, c3_b1, c3_w2, c3_b2, Abuf);
  conv_mfma_kernel<32, 32, 64, 2, true><<<N2C/2, 256, 0, stream>>>(
      h2, knn3, Abuf, wb3, c3_bs, sc2, sh2, h3, gpart);
  bn_finalize_kernel<<<64, 256, 0, stream>>>(gpart, N2C/2, 64, bn3_g, bn3_b, sc3, sh3, invN);

  pool_kernel<<<N3C/16, 256, 0, stream>>>(h3, pidx, sc3, sh3, (float*)d_out);
}

// Round 4
// 208.787 us; speedup vs baseline: 3.5117x; 1.0105x over previous
//
#include <hip/hip_runtime.h>
#include <hip/hip_bf16.h>
#include <cfloat>

#define N1C 50176
#define N2C 12544
#define N3C 3136

typedef __attribute__((ext_vector_type(8))) short short8v;
typedef __attribute__((ext_vector_type(4))) float f32x4;

static __device__ __forceinline__ unsigned short f2bf(float f){
  __hip_bfloat16 h = __float2bfloat16(f);
  return *reinterpret_cast<unsigned short*>(&h);
}
static __device__ __forceinline__ float bflo(unsigned v){
  return __uint_as_float(v << 16);
}
static __device__ __forceinline__ float bfhi(unsigned v){
  return __uint_as_float(v & 0xFFFF0000u);
}
static __device__ __forceinline__ float bf2f(unsigned short u){
  return __uint_as_float(((unsigned)u) << 16);
}

// ---------------- transpose x: (16,3,N1) f32 -> xTb (N1, 16, 4) bf16 ----
__global__ __launch_bounds__(256) void transpose_x_kernel(
    const float* __restrict__ x, unsigned short* __restrict__ xTb)
{
  __shared__ float tile[48][65];
  int n0 = blockIdx.x * 64;
  int tid = threadIdx.x;
  int i = tid & 63;
  for (int rr = tid >> 6; rr < 48; rr += 4)
    tile[rr][i] = x[(size_t)rr * N1C + n0 + i];
  __syncthreads();
  for (int j = tid; j < 64*64; j += 256){
    int ii = j >> 6, bc = j & 63, b = bc >> 2, c = bc & 3;
    float v = (c < 3) ? tile[b*3 + c][ii] : 0.f;
    xTb[(size_t)n0 * 64 + j] = f2bf(v);
  }
}

// ---------------- A[n,k,t] = (relu(off @ w1 + b1) @ w2 + b2) ----------------
__global__ __launch_bounds__(256) void compute_A_kernel(
    const float* __restrict__ pos_in, const float* __restrict__ pos_out,
    const int* __restrict__ idx,
    const float* __restrict__ w1, const float* __restrict__ b1,
    const float* __restrict__ w2, const float* __restrict__ b2,
    float* __restrict__ Abuf)
{
  int g = blockIdx.x * 256 + threadIdx.x;
  if (g >= N2C * 9) return;
  int n = g / 9;
  int p = idx[g];
  float o0 = pos_in[2*p]   - pos_out[2*n];
  float o1 = pos_in[2*p+1] - pos_out[2*n+1];
  float A[9];
  #pragma unroll
  for (int t = 0; t < 9; t++) A[t] = b2[t];
  #pragma unroll
  for (int j = 0; j < 16; j++){
    float h = fmaxf(fmaf(o0, w1[j], fmaf(o1, w1[16+j], b1[j])), 0.f);
    #pragma unroll
    for (int t = 0; t < 9; t++) A[t] = fmaf(h, w2[j*9 + t], A[t]);
  }
  #pragma unroll
  for (int t = 0; t < 9; t++) Abuf[(size_t)g*9 + t] = A[t];
}

// ---------------- W (o,k) f32 -> Wb[o][k] bf16, zero-padded to KW --------
__global__ __launch_bounds__(256) void wcvt_kernel(
    const float* __restrict__ W, unsigned short* __restrict__ Wb,
    int total, int K, int KW)
{
  int i = blockIdx.x * 256 + threadIdx.x;
  if (i >= total) return;
  int o = i / KW, k = i % KW;
  Wb[i] = f2bf(k < K ? W[o*K + k] : 0.f);
}

// ======== conv1 path (small CIN), as round-3 ========
template<int CIN, int CINP, int COUT, int NPB, bool AFFINE>
__global__ __launch_bounds__(256) void conv_mfma_kernel(
    const unsigned short* __restrict__ in, const int* __restrict__ idx,
    const float* __restrict__ Abuf, const unsigned short* __restrict__ Wb,
    const float* __restrict__ bias,
    const float* __restrict__ scale, const float* __restrict__ shift,
    unsigned short* __restrict__ out, float* __restrict__ gpart)
{
  constexpr int K    = CIN * 9;
  constexpr int KW   = (K < 32) ? 32 : K;
  constexpr int KROW = (K < 32) ? 48 : 296;
  constexpr int CHUNKS = KW / 32;
  constexpr int OT   = COUT / 16;
  constexpr int HP   = CINP / 2;
  constexpr int PPT  = 16 * HP;

  __shared__ alignas(16) unsigned short Tb[NPB * 16 * KROW];
  __shared__ float As[NPB * 81];
  __shared__ int   Ip[NPB * 9];
  __shared__ float Sw[4 * COUT];
  __shared__ float Sq[4 * COUT];

  int n0 = blockIdx.x * NPB;
  int tid = threadIdx.x;
  for (int i = tid; i < NPB*81; i += 256) As[i] = Abuf[(size_t)n0*81 + i];
  if (tid < NPB*9) Ip[tid] = idx[n0*9 + tid];
  for (int i = tid; i < 4*COUT; i += 256){ Sw[i] = 0.f; Sq[i] = 0.f; }
  if (K < 32){
    for (int i = tid; i < NPB*16*KROW/2; i += 256) ((unsigned*)Tb)[i] = 0u;
  }
  __syncthreads();

  for (int u = tid; u < NPB*PPT; u += 256){
    int ni = u / PPT, loc = u % PPT;
    int b = loc / HP, c2 = loc % HP;
    const float* As_n = As + ni*81;
    const int*   ip   = Ip + ni*9;
    float scx=1.f, shx=0.f, scy=1.f, shy=0.f;
    if (AFFINE){
      scx = scale[2*c2];   shx = shift[2*c2];
      scy = scale[2*c2+1]; shy = shift[2*c2+1];
    }
    float fx[9], fy[9];
    #pragma unroll
    for (int k = 0; k < 9; k++){
      unsigned v = *(const unsigned*)(in + ((size_t)ip[k]*16 + b)*CINP + 2*c2);
      float x0 = bflo(v), y0 = bfhi(v);
      if (AFFINE){
        x0 = fmaxf(fmaf(x0, scx, shx), 0.f);
        y0 = fmaxf(fmaf(y0, scy, shy), 0.f);
      }
      fx[k] = x0; fy[k] = y0;
    }
    unsigned short e[18];
    #pragma unroll
    for (int t = 0; t < 9; t++){
      float s0 = 0.f, s1 = 0.f;
      #pragma unroll
      for (int k = 0; k < 9; k++){
        float a = As_n[k*9 + t];
        s0 = fmaf(fx[k], a, s0);
        s1 = fmaf(fy[k], a, s1);
      }
      e[t] = f2bf(s0); e[9+t] = f2bf(s1);
    }
    unsigned* dst = (unsigned*)(Tb + (ni*16 + b)*KROW + 18*c2);
    #pragma unroll
    for (int j = 0; j < 9; j++) dst[j] = (unsigned)e[2*j] | ((unsigned)e[2*j+1] << 16);
  }
  __syncthreads();

  int w = tid >> 6, l = tid & 63, lr = l & 15, lg = l >> 4;
  float smr[4] = {0,0,0,0}, sqr[4] = {0,0,0,0};
  int oBase = 0;
  for (int wi = w; wi < NPB*OT; wi += 4){
    int ni = wi / OT, ot = wi % OT;
    oBase = 16*ot + 4*lg;
    f32x4 acc;
    #pragma unroll
    for (int r = 0; r < 4; r++) acc[r] = bias[oBase + r];
    const short8v* ap = (const short8v*)(Wb + (size_t)(16*ot + lr)*KW) + lg;
    const short8v* bp = (const short8v*)(Tb + (ni*16 + lr)*KROW) + lg;
    #pragma unroll
    for (int kk = 0; kk < CHUNKS; kk++)
      acc = __builtin_amdgcn_mfma_f32_16x16x32_bf16(ap[kk*4], bp[kk*4], acc, 0, 0, 0);
    ushort4 o4;
    o4.x = f2bf(acc[0]); o4.y = f2bf(acc[1]); o4.z = f2bf(acc[2]); o4.w = f2bf(acc[3]);
    *(ushort4*)(out + ((size_t)(n0 + ni)*16 + lr)*COUT + oBase) = o4;
    #pragma unroll
    for (int r = 0; r < 4; r++){
      smr[r] += acc[r];
      sqr[r] = fmaf(acc[r], acc[r], sqr[r]);
    }
  }
  #pragma unroll
  for (int m = 1; m < 16; m <<= 1){
    #pragma unroll
    for (int r = 0; r < 4; r++){
      smr[r] += __shfl_xor(smr[r], m);
      sqr[r] += __shfl_xor(sqr[r], m);
    }
  }
  if (lr == 0){
    #pragma unroll
    for (int r = 0; r < 4; r++){
      Sw[w*COUT + oBase + r] = smr[r];
      Sq[w*COUT + oBase + r] = sqr[r];
    }
  }
  __syncthreads();
  for (int o = tid; o < COUT; o += 256){
    float sm = Sw[o] + Sw[COUT + o] + Sw[2*COUT + o] + Sw[3*COUT + o];
    float sq = Sq[o] + Sq[COUT + o] + Sq[2*COUT + o] + Sq[3*COUT + o];
    gpart[(size_t)blockIdx.x * 2*COUT + o] = sm;
    gpart[(size_t)blockIdx.x * 2*COUT + COUT + o] = sq;
  }
}

// ======== conv2/3 path: wave-per-point, A in regs, saddr gather ========
// in: (N2, 16, 32) bf16; out: (N2, 16, COUT) bf16. CIN=32 fixed, AFFINE.
template<int COUT>
__global__ __launch_bounds__(256, 3) void conv_wave_kernel(
    const unsigned short* __restrict__ in, const int* __restrict__ idx,
    const float* __restrict__ Abuf, const unsigned short* __restrict__ Wb,
    const float* __restrict__ bias,
    const float* __restrict__ scale, const float* __restrict__ shift,
    unsigned short* __restrict__ out, float* __restrict__ gpart)
{
  constexpr int NPB  = 4;
  constexpr int KROW = 296;            // shorts per taps row (K=288 + stagger pad)
  constexpr int OT   = COUT / 16;

  __shared__ alignas(16) unsigned short Tb[NPB * 16 * KROW];  // 37,888 B
  __shared__ float Sw[4 * COUT];
  __shared__ float Sq[4 * COUT];
  __shared__ float Ssc[32], Ssh[32];

  int tid = threadIdx.x;
  int w = tid >> 6, l = tid & 63;
  int n0 = blockIdx.x * NPB;
  if (tid < 32){ Ssc[tid] = scale[tid]; Ssh[tid] = shift[tid]; }
  for (int i = tid; i < 4*COUT; i += 256){ Sw[i] = 0.f; Sq[i] = 0.f; }
  __syncthreads();

  // wave-uniform point id, scalarized
  int nws = __builtin_amdgcn_readfirstlane(n0 + w);

  // A[81] into registers (broadcast loads, L1-hit after first wave)
  float areg[81];
  {
    const float* Ap = Abuf + (size_t)nws * 81;
    #pragma unroll
    for (int j = 0; j < 81; j++) areg[j] = Ap[j];
  }
  // knn row via uniform address -> s_load
  int ip[9];
  {
    const int* ipr = idx + nws * 9;
    #pragma unroll
    for (int k = 0; k < 9; k++) ip[k] = ipr[k];
  }

  // ---- phase 2: 4 units per thread, all of this wave's point ----
  int c2 = l & 15;
  float scx = Ssc[2*c2],   shx = Ssh[2*c2];
  float scy = Ssc[2*c2+1], shy = Ssh[2*c2+1];
  for (int j = 0; j < 4; j++){
    int b = (l >> 4) * 4 + j;
    unsigned off = (unsigned)(b*32 + 2*c2);      // shorts within input row
    float fx[9], fy[9];
    #pragma unroll
    for (int k = 0; k < 9; k++){
      const unsigned short* rp = in + (size_t)ip[k] * 512;   // SGPR base
      unsigned v = *(const unsigned*)(rp + off);
      float x0 = fmaxf(fmaf(bflo(v), scx, shx), 0.f);
      float y0 = fmaxf(fmaf(bfhi(v), scy, shy), 0.f);
      fx[k] = x0; fy[k] = y0;
    }
    unsigned short e[18];
    #pragma unroll
    for (int t = 0; t < 9; t++){
      float s0 = 0.f, s1 = 0.f;
      #pragma unroll
      for (int k = 0; k < 9; k++){
        float a = areg[k*9 + t];
        s0 = fmaf(fx[k], a, s0);
        s1 = fmaf(fy[k], a, s1);
      }
      e[t] = f2bf(s0); e[9+t] = f2bf(s1);
    }
    unsigned* dst = (unsigned*)(Tb + (w*16 + b)*KROW + 18*c2);
    #pragma unroll
    for (int q = 0; q < 9; q++) dst[q] = (unsigned)e[2*q] | ((unsigned)e[2*q+1] << 16);
  }
  __syncthreads();

  // ---- phase 3: MFMA D(16x16) = W(16x288) . taps(288x16) ----
  int lr = l & 15, lg = l >> 4;
  float smr[4] = {0,0,0,0}, sqr[4] = {0,0,0,0};
  int oBase = 0;
  for (int wi = w; wi < NPB*OT; wi += 4){
    int ni = wi / OT, ot = wi % OT;
    oBase = 16*ot + 4*lg;
    f32x4 acc;
    #pragma unroll
    for (int r = 0; r < 4; r++) acc[r] = bias[oBase + r];
    const short8v* ap = (const short8v*)(Wb + (size_t)(16*ot + lr)*288) + lg;
    const short8v* bp = (const short8v*)(Tb + (ni*16 + lr)*KROW) + lg;
    #pragma unroll
    for (int kk = 0; kk < 9; kk++)
      acc = __builtin_amdgcn_mfma_f32_16x16x32_bf16(ap[kk*4], bp[kk*4], acc, 0, 0, 0);
    ushort4 o4;
    o4.x = f2bf(acc[0]); o4.y = f2bf(acc[1]); o4.z = f2bf(acc[2]); o4.w = f2bf(acc[3]);
    *(ushort4*)(out + ((size_t)(n0 + ni)*16 + lr)*COUT + oBase) = o4;
    #pragma unroll
    for (int r = 0; r < 4; r++){
      smr[r] += acc[r];
      sqr[r] = fmaf(acc[r], acc[r], sqr[r]);
    }
  }
  #pragma unroll
  for (int m = 1; m < 16; m <<= 1){
    #pragma unroll
    for (int r = 0; r < 4; r++){
      smr[r] += __shfl_xor(smr[r], m);
      sqr[r] += __shfl_xor(sqr[r], m);
    }
  }
  if (lr == 0){
    #pragma unroll
    for (int r = 0; r < 4; r++){
      Sw[w*COUT + oBase + r] = smr[r];
      Sq[w*COUT + oBase + r] = sqr[r];
    }
  }
  __syncthreads();
  for (int o = tid; o < COUT; o += 256){
    float sm = Sw[o] + Sw[COUT + o] + Sw[2*COUT + o] + Sw[3*COUT + o];
    float sq = Sq[o] + Sq[COUT + o] + Sq[2*COUT + o] + Sq[3*COUT + o];
    gpart[(size_t)blockIdx.x * 2*COUT + o] = sm;
    gpart[(size_t)blockIdx.x * 2*COUT + COUT + o] = sq;
  }
}

// ---------------- finalize BN ----------------
__global__ __launch_bounds__(256) void bn_finalize_kernel(
    const float* __restrict__ gpart, int NB, int C,
    const float* __restrict__ g, const float* __restrict__ bb,
    float* __restrict__ sc, float* __restrict__ sh, float invN)
{
  int c = blockIdx.x;
  float sm = 0.f, sq = 0.f;
  for (int i = threadIdx.x; i < NB; i += 256){
    sm += gpart[(size_t)i*2*C + c];
    sq += gpart[(size_t)i*2*C + C + c];
  }
  #pragma unroll
  for (int off = 32; off > 0; off >>= 1){
    sm += __shfl_down(sm, off);
    sq += __shfl_down(sq, off);
  }
  __shared__ float rs[8];
  int wd = threadIdx.x >> 6, ln = threadIdx.x & 63;
  if (ln == 0){ rs[wd] = sm; rs[4+wd] = sq; }
  __syncthreads();
  if (threadIdx.x == 0){
    float S = rs[0]+rs[1]+rs[2]+rs[3], Q = rs[4]+rs[5]+rs[6]+rs[7];
    float mean = S * invN;
    float var  = fmaxf(Q * invN - mean*mean, 0.f);
    float s = g[c] * rsqrtf(var + 1e-5f);
    sc[c] = s;
    sh[c] = bb[c] - mean * s;
  }
}

// ------------- BN3 + relu + max-pool + write (16,64,N3) f32 -------------
__global__ __launch_bounds__(256) void pool_kernel(
    const unsigned short* __restrict__ h3, const int* __restrict__ pidx,
    const float* __restrict__ sc, const float* __restrict__ sh,
    float* __restrict__ out)
{
  __shared__ float P[16][1024];
  int m0 = blockIdx.x * 16;
  int tid = threadIdx.x;
  for (int mi = 0; mi < 16; mi++){
    int m = m0 + mi;
    int p0 = pidx[m*4+0], p1 = pidx[m*4+1], p2 = pidx[m*4+2], p3 = pidx[m*4+3];
    #pragma unroll
    for (int q = 0; q < 4; q++){
      int bo = tid + q*256;
      int o = bo & 63;
      float s = sc[o], h = sh[o];
      float v0 = fmaf(bf2f(h3[(size_t)p0*1024 + bo]), s, h);
      float v1 = fmaf(bf2f(h3[(size_t)p1*1024 + bo]), s, h);
      float v2 = fmaf(bf2f(h3[(size_t)p2*1024 + bo]), s, h);
      float v3 = fmaf(bf2f(h3[(size_t)p3*1024 + bo]), s, h);
      P[mi][bo] = fmaxf(fmaxf(fmaxf(v0,v1), fmaxf(v2,v3)), 0.f);
    }
  }
  __syncthreads();
  #pragma unroll
  for (int w = 0; w < 4; w++){
    int r = tid + w*256;
    float* dst = out + (size_t)r*N3C + m0;
    #pragma unroll
    for (int mi = 0; mi < 16; mi++) dst[mi] = P[mi][r];
  }
}

// ---------------- launch ----------------
extern "C" void kernel_launch(void* const* d_in, const int* in_sizes, int n_in,
                              void* d_out, int out_size, void* d_ws, size_t ws_size,
                              hipStream_t stream)
{
  const float* x    = (const float*)d_in[0];
  const float* l1   = (const float*)d_in[1];
  const float* l2   = (const float*)d_in[2];
  const int* knn1   = (const int*)d_in[4];
  const int* knn2   = (const int*)d_in[5];
  const int* knn3   = (const int*)d_in[6];
  const int* pidx   = (const int*)d_in[7];

  const float* c1_w1 = (const float*)d_in[8];
  const float* c1_b1 = (const float*)d_in[9];
  const float* c1_w2 = (const float*)d_in[10];
  const float* c1_b2 = (const float*)d_in[11];
  const float* c1_k  = (const float*)d_in[12];
  const float* c1_bs = (const float*)d_in[13];
  const float* c2_w1 = (const float*)d_in[14];
  const float* c2_b1 = (const float*)d_in[15];
  const float* c2_w2 = (const float*)d_in[16];
  const float* c2_b2 = (const float*)d_in[17];
  const float* c2_k  = (const float*)d_in[18];
  const float* c2_bs = (const float*)d_in[19];
  const float* c3_w1 = (const float*)d_in[20];
  const float* c3_b1 = (const float*)d_in[21];
  const float* c3_w2 = (const float*)d_in[22];
  const float* c3_b2 = (const float*)d_in[23];
  const float* c3_k  = (const float*)d_in[24];
  const float* c3_bs = (const float*)d_in[25];
  const float* bn1_g = (const float*)d_in[26];
  const float* bn1_b = (const float*)d_in[27];
  const float* bn2_g = (const float*)d_in[28];
  const float* bn2_b = (const float*)d_in[29];
  const float* bn3_g = (const float*)d_in[30];
  const float* bn3_b = (const float*)d_in[31];

  char* ws = (char*)d_ws;
  unsigned short* xTb = (unsigned short*)(ws + 0);
  unsigned short* h1  = (unsigned short*)(ws + 6422528);
  unsigned short* h2  = (unsigned short*)(ws + 19267584);
  unsigned short* h3  = (unsigned short*)(ws + 32112640);
  float* Abuf         = (float*)(ws + 57802752);
  float* gpart        = (float*)(ws + 61867008);
  unsigned short* wb1 = (unsigned short*)(ws + 65078272);
  unsigned short* wb2 = (unsigned short*)(ws + 65081344);
  unsigned short* wb3 = (unsigned short*)(ws + 65099776);
  float* sc1 = (float*)(ws + 65137664); float* sh1 = sc1 + 32;
  float* sc2 = sh1 + 32;                float* sh2 = sc2 + 32;
  float* sc3 = sh2 + 32;                float* sh3 = sc3 + 64;

  const float invN = 1.0f / (float)(N2C * 16);
  const int ablocks = (N2C * 9 + 255) / 256;

  transpose_x_kernel<<<N1C/64, 256, 0, stream>>>(x, xTb);
  wcvt_kernel<<<(32*32 + 255)/256, 256, 0, stream>>>(c1_k, wb1, 32*32, 27, 32);
  wcvt_kernel<<<(32*288 + 255)/256, 256, 0, stream>>>(c2_k, wb2, 32*288, 288, 288);
  wcvt_kernel<<<(64*288 + 255)/256, 256, 0, stream>>>(c3_k, wb3, 64*288, 288, 288);

  // conv1 (old path)
  compute_A_kernel<<<ablocks, 256, 0, stream>>>(l1, l2, knn1, c1_w1, c1_b1, c1_w2, c1_b2, Abuf);
  conv_mfma_kernel<3, 4, 32, 8, false><<<N2C/8, 256, 0, stream>>>(
      xTb, knn1, Abuf, wb1, c1_bs, nullptr, nullptr, h1, gpart);
  bn_finalize_kernel<<<32, 256, 0, stream>>>(gpart, N2C/8, 32, bn1_g, bn1_b, sc1, sh1, invN);

  // conv2 (wave-per-point)
  compute_A_kernel<<<ablocks, 256, 0, stream>>>(l2, l2, knn2, c2_w1, c2_b1, c2_w2, c2_b2, Abuf);
  conv_wave_kernel<32><<<N2C/4, 256, 0, stream>>>(
      h1, knn2, Abuf, wb2, c2_bs, sc1, sh1, h2, gpart);
  bn_finalize_kernel<<<32, 256, 0, stream>>>(gpart, N2C/4, 32, bn2_g, bn2_b, sc2, sh2, invN);

  // conv3 (wave-per-point)
  compute_A_kernel<<<ablocks, 256, 0, stream>>>(l2, l2, knn3, c3_w1, c3_b1, c3_w2, c3_b2, Abuf);
  conv_wave_kernel<64><<<N2C/4, 256, 0, stream>>>(
      h2, knn3, Abuf, wb3, c3_bs, sc2, sh2, h3, gpart);
  bn_finalize_kernel<<<64, 256, 0, stream>>>(gpart, N2C/4, 64, bn3_g, bn3_b, sc3, sh3, invN);

  pool_kernel<<<N3C/16, 256, 0, stream>>>(h3, pidx, sc3, sh3, (float*)d_out);
}

// Round 5
// 175.854 us; speedup vs baseline: 4.1694x; 1.1873x over previous
//
#include <hip/hip_runtime.h>
#include <hip/hip_bf16.h>
#include <cfloat>

#define N1C 50176
#define N2C 12544
#define N3C 3136

typedef __attribute__((ext_vector_type(8))) short short8v;
typedef __attribute__((ext_vector_type(4))) float f32x4;

static __device__ __forceinline__ unsigned short f2bf(float f){
  __hip_bfloat16 h = __float2bfloat16(f);
  return *reinterpret_cast<unsigned short*>(&h);
}
static __device__ __forceinline__ float bflo(unsigned v){
  return __uint_as_float(v << 16);
}
static __device__ __forceinline__ float bfhi(unsigned v){
  return __uint_as_float(v & 0xFFFF0000u);
}
static __device__ __forceinline__ float bf2f(unsigned short u){
  return __uint_as_float(((unsigned)u) << 16);
}

// ---------------- transpose x: (16,3,N1) f32 -> xTb (N1, 16, 4) bf16 ----
__global__ __launch_bounds__(256) void transpose_x_kernel(
    const float* __restrict__ x, unsigned short* __restrict__ xTb)
{
  __shared__ float tile[48][65];
  int n0 = blockIdx.x * 64;
  int tid = threadIdx.x;
  int i = tid & 63;
  for (int rr = tid >> 6; rr < 48; rr += 4)
    tile[rr][i] = x[(size_t)rr * N1C + n0 + i];
  __syncthreads();
  for (int j = tid; j < 64*64; j += 256){
    int ii = j >> 6, bc = j & 63, b = bc >> 2, c = bc & 3;
    float v = (c < 3) ? tile[b*3 + c][ii] : 0.f;
    xTb[(size_t)n0 * 64 + j] = f2bf(v);
  }
}

// ---------------- A[n,k,t] = (relu(off @ w1 + b1) @ w2 + b2) ----------------
__global__ __launch_bounds__(256) void compute_A_kernel(
    const float* __restrict__ pos_in, const float* __restrict__ pos_out,
    const int* __restrict__ idx,
    const float* __restrict__ w1, const float* __restrict__ b1,
    const float* __restrict__ w2, const float* __restrict__ b2,
    float* __restrict__ Abuf)
{
  int g = blockIdx.x * 256 + threadIdx.x;
  if (g >= N2C * 9) return;
  int n = g / 9;
  int p = idx[g];
  float o0 = pos_in[2*p]   - pos_out[2*n];
  float o1 = pos_in[2*p+1] - pos_out[2*n+1];
  float A[9];
  #pragma unroll
  for (int t = 0; t < 9; t++) A[t] = b2[t];
  #pragma unroll
  for (int j = 0; j < 16; j++){
    float h = fmaxf(fmaf(o0, w1[j], fmaf(o1, w1[16+j], b1[j])), 0.f);
    #pragma unroll
    for (int t = 0; t < 9; t++) A[t] = fmaf(h, w2[j*9 + t], A[t]);
  }
  #pragma unroll
  for (int t = 0; t < 9; t++) Abuf[(size_t)g*9 + t] = A[t];
}

// ---------------- W (o,k) f32 -> Wb[o][k] bf16, zero-padded to KW --------
__global__ __launch_bounds__(256) void wcvt_kernel(
    const float* __restrict__ W, unsigned short* __restrict__ Wb,
    int total, int K, int KW)
{
  int i = blockIdx.x * 256 + threadIdx.x;
  if (i >= total) return;
  int o = i / KW, k = i % KW;
  Wb[i] = f2bf(k < K ? W[o*K + k] : 0.f);
}

// ======== conv1 path (small CIN) ========
template<int CIN, int CINP, int COUT, int NPB, bool AFFINE>
__global__ __launch_bounds__(256) void conv_mfma_kernel(
    const unsigned short* __restrict__ in, const int* __restrict__ idx,
    const float* __restrict__ Abuf, const unsigned short* __restrict__ Wb,
    const float* __restrict__ bias,
    const float* __restrict__ scale, const float* __restrict__ shift,
    unsigned short* __restrict__ out, float* __restrict__ gpart)
{
  constexpr int K    = CIN * 9;
  constexpr int KW   = (K < 32) ? 32 : K;
  constexpr int KROW = (K < 32) ? 48 : 296;
  constexpr int CHUNKS = KW / 32;
  constexpr int OT   = COUT / 16;
  constexpr int HP   = CINP / 2;
  constexpr int PPT  = 16 * HP;

  __shared__ alignas(16) unsigned short Tb[NPB * 16 * KROW];
  __shared__ float As[NPB * 81];
  __shared__ int   Ip[NPB * 9];
  __shared__ float Sw[4 * COUT];
  __shared__ float Sq[4 * COUT];

  int n0 = blockIdx.x * NPB;
  int tid = threadIdx.x;
  for (int i = tid; i < NPB*81; i += 256) As[i] = Abuf[(size_t)n0*81 + i];
  if (tid < NPB*9) Ip[tid] = idx[n0*9 + tid];
  for (int i = tid; i < 4*COUT; i += 256){ Sw[i] = 0.f; Sq[i] = 0.f; }
  if (K < 32){
    for (int i = tid; i < NPB*16*KROW/2; i += 256) ((unsigned*)Tb)[i] = 0u;
  }
  __syncthreads();

  for (int u = tid; u < NPB*PPT; u += 256){
    int ni = u / PPT, loc = u % PPT;
    int b = loc / HP, c2 = loc % HP;
    const float* As_n = As + ni*81;
    const int*   ip   = Ip + ni*9;
    float scx=1.f, shx=0.f, scy=1.f, shy=0.f;
    if (AFFINE){
      scx = scale[2*c2];   shx = shift[2*c2];
      scy = scale[2*c2+1]; shy = shift[2*c2+1];
    }
    float fx[9], fy[9];
    #pragma unroll
    for (int k = 0; k < 9; k++){
      unsigned v = *(const unsigned*)(in + ((size_t)ip[k]*16 + b)*CINP + 2*c2);
      float x0 = bflo(v), y0 = bfhi(v);
      if (AFFINE){
        x0 = fmaxf(fmaf(x0, scx, shx), 0.f);
        y0 = fmaxf(fmaf(y0, scy, shy), 0.f);
      }
      fx[k] = x0; fy[k] = y0;
    }
    unsigned short e[18];
    #pragma unroll
    for (int t = 0; t < 9; t++){
      float s0 = 0.f, s1 = 0.f;
      #pragma unroll
      for (int k = 0; k < 9; k++){
        float a = As_n[k*9 + t];
        s0 = fmaf(fx[k], a, s0);
        s1 = fmaf(fy[k], a, s1);
      }
      e[t] = f2bf(s0); e[9+t] = f2bf(s1);
    }
    unsigned* dst = (unsigned*)(Tb + (ni*16 + b)*KROW + 18*c2);
    #pragma unroll
    for (int j = 0; j < 9; j++) dst[j] = (unsigned)e[2*j] | ((unsigned)e[2*j+1] << 16);
  }
  __syncthreads();

  int w = tid >> 6, l = tid & 63, lr = l & 15, lg = l >> 4;
  float smr[4] = {0,0,0,0}, sqr[4] = {0,0,0,0};
  int oBase = 0;
  for (int wi = w; wi < NPB*OT; wi += 4){
    int ni = wi / OT, ot = wi % OT;
    oBase = 16*ot + 4*lg;
    f32x4 acc;
    #pragma unroll
    for (int r = 0; r < 4; r++) acc[r] = bias[oBase + r];
    const short8v* ap = (const short8v*)(Wb + (size_t)(16*ot + lr)*KW) + lg;
    const short8v* bp = (const short8v*)(Tb + (ni*16 + lr)*KROW) + lg;
    #pragma unroll
    for (int kk = 0; kk < CHUNKS; kk++)
      acc = __builtin_amdgcn_mfma_f32_16x16x32_bf16(ap[kk*4], bp[kk*4], acc, 0, 0, 0);
    ushort4 o4;
    o4.x = f2bf(acc[0]); o4.y = f2bf(acc[1]); o4.z = f2bf(acc[2]); o4.w = f2bf(acc[3]);
    *(ushort4*)(out + ((size_t)(n0 + ni)*16 + lr)*COUT + oBase) = o4;
    #pragma unroll
    for (int r = 0; r < 4; r++){
      smr[r] += acc[r];
      sqr[r] = fmaf(acc[r], acc[r], sqr[r]);
    }
  }
  #pragma unroll
  for (int m = 1; m < 16; m <<= 1){
    #pragma unroll
    for (int r = 0; r < 4; r++){
      smr[r] += __shfl_xor(smr[r], m);
      sqr[r] += __shfl_xor(sqr[r], m);
    }
  }
  if (lr == 0){
    #pragma unroll
    for (int r = 0; r < 4; r++){
      Sw[w*COUT + oBase + r] = smr[r];
      Sq[w*COUT + oBase + r] = sqr[r];
    }
  }
  __syncthreads();
  for (int o = tid; o < COUT; o += 256){
    float sm = Sw[o] + Sw[COUT + o] + Sw[2*COUT + o] + Sw[3*COUT + o];
    float sq = Sq[o] + Sq[COUT + o] + Sq[2*COUT + o] + Sq[3*COUT + o];
    gpart[(size_t)blockIdx.x * 2*COUT + o] = sm;
    gpart[(size_t)blockIdx.x * 2*COUT + COUT + o] = sq;
  }
}

// ======== conv2/3: wave-per-point, dwordx4 gather (8 ch/lane, 9 loads) ========
// in: (N2, 16, 32) bf16; out: (N2, 16, COUT) bf16. CIN=32, AFFINE.
template<int COUT>
__global__ __launch_bounds__(256, 4) void conv_wave_kernel(
    const unsigned short* __restrict__ in, const int* __restrict__ idx,
    const float* __restrict__ Abuf, const unsigned short* __restrict__ Wb,
    const float* __restrict__ bias,
    const float* __restrict__ scale, const float* __restrict__ shift,
    unsigned short* __restrict__ out, float* __restrict__ gpart)
{
  constexpr int NPB  = 4;
  constexpr int KROW = 296;
  constexpr int OT   = COUT / 16;

  __shared__ alignas(16) unsigned short Tb[NPB * 16 * KROW];  // 37,888 B
  __shared__ float Sw[4 * COUT];
  __shared__ float Sq[4 * COUT];
  __shared__ float Ssc[32], Ssh[32];

  int tid = threadIdx.x;
  int w = tid >> 6, l = tid & 63;
  int n0 = blockIdx.x * NPB;
  if (tid < 32){ Ssc[tid] = scale[tid]; Ssh[tid] = shift[tid]; }
  for (int i = tid; i < 4*COUT; i += 256){ Sw[i] = 0.f; Sq[i] = 0.f; }
  __syncthreads();

  int nws = __builtin_amdgcn_readfirstlane(n0 + w);

  // A[81] (wave-uniform -> scalar loads)
  float areg[81];
  {
    const float* Ap = Abuf + (size_t)nws * 81;
    #pragma unroll
    for (int j = 0; j < 81; j++) areg[j] = Ap[j];
  }
  int ip[9];
  {
    const int* ipr = idx + nws * 9;
    #pragma unroll
    for (int k = 0; k < 9; k++) ip[k] = ipr[k];
  }

  // ---- phase 2: lane = (b, 8-channel group); 9x dwordx4 gather ----
  int b = l & 15, cg = l >> 4;
  float scv[8], shv[8];
  #pragma unroll
  for (int p = 0; p < 8; p++){ scv[p] = Ssc[cg*8 + p]; shv[p] = Ssh[cg*8 + p]; }

  uint4 rv[9];
  #pragma unroll
  for (int k = 0; k < 9; k++){
    const unsigned short* rp = in + (size_t)ip[k]*512 + b*32 + cg*8;
    rv[k] = *(const uint4*)rp;
  }

  float acc[72];
  #pragma unroll
  for (int i = 0; i < 72; i++) acc[i] = 0.f;
  #pragma unroll
  for (int k = 0; k < 9; k++){
    unsigned uu[4] = {rv[k].x, rv[k].y, rv[k].z, rv[k].w};
    #pragma unroll
    for (int p = 0; p < 4; p++){
      float x0 = fmaxf(fmaf(bflo(uu[p]), scv[2*p],   shv[2*p]),   0.f);
      float y0 = fmaxf(fmaf(bfhi(uu[p]), scv[2*p+1], shv[2*p+1]), 0.f);
      #pragma unroll
      for (int t = 0; t < 9; t++){
        float a = areg[k*9 + t];
        acc[(2*p)*9 + t]   = fmaf(x0, a, acc[(2*p)*9 + t]);
        acc[(2*p+1)*9 + t] = fmaf(y0, a, acc[(2*p+1)*9 + t]);
      }
    }
  }
  // pack 72 f32 -> 72 bf16, one contiguous 144 B region per thread
  uint4* dst4 = (uint4*)(Tb + (w*16 + b)*KROW + cg*72);
  #pragma unroll
  for (int q = 0; q < 9; q++){
    uint4 o;
    o.x = (unsigned)f2bf(acc[8*q+0]) | ((unsigned)f2bf(acc[8*q+1]) << 16);
    o.y = (unsigned)f2bf(acc[8*q+2]) | ((unsigned)f2bf(acc[8*q+3]) << 16);
    o.z = (unsigned)f2bf(acc[8*q+4]) | ((unsigned)f2bf(acc[8*q+5]) << 16);
    o.w = (unsigned)f2bf(acc[8*q+6]) | ((unsigned)f2bf(acc[8*q+7]) << 16);
    dst4[q] = o;
  }
  __syncthreads();

  // ---- phase 3: MFMA D(16x16) = W(16x288) . taps(288x16) ----
  int lr = l & 15, lg = l >> 4;
  float smr[4] = {0,0,0,0}, sqr[4] = {0,0,0,0};
  int oBase = 0;
  for (int wi = w; wi < NPB*OT; wi += 4){
    int ni = wi / OT, ot = wi % OT;
    oBase = 16*ot + 4*lg;
    f32x4 acc3;
    #pragma unroll
    for (int r = 0; r < 4; r++) acc3[r] = bias[oBase + r];
    const short8v* ap = (const short8v*)(Wb + (size_t)(16*ot + lr)*288) + lg;
    const short8v* bp = (const short8v*)(Tb + (ni*16 + lr)*KROW) + lg;
    #pragma unroll
    for (int kk = 0; kk < 9; kk++)
      acc3 = __builtin_amdgcn_mfma_f32_16x16x32_bf16(ap[kk*4], bp[kk*4], acc3, 0, 0, 0);
    ushort4 o4;
    o4.x = f2bf(acc3[0]); o4.y = f2bf(acc3[1]); o4.z = f2bf(acc3[2]); o4.w = f2bf(acc3[3]);
    *(ushort4*)(out + ((size_t)(n0 + ni)*16 + lr)*COUT + oBase) = o4;
    #pragma unroll
    for (int r = 0; r < 4; r++){
      smr[r] += acc3[r];
      sqr[r] = fmaf(acc3[r], acc3[r], sqr[r]);
    }
  }
  #pragma unroll
  for (int m = 1; m < 16; m <<= 1){
    #pragma unroll
    for (int r = 0; r < 4; r++){
      smr[r] += __shfl_xor(smr[r], m);
      sqr[r] += __shfl_xor(sqr[r], m);
    }
  }
  if (lr == 0){
    #pragma unroll
    for (int r = 0; r < 4; r++){
      Sw[w*COUT + oBase + r] = smr[r];
      Sq[w*COUT + oBase + r] = sqr[r];
    }
  }
  __syncthreads();
  for (int o = tid; o < COUT; o += 256){
    float sm = Sw[o] + Sw[COUT + o] + Sw[2*COUT + o] + Sw[3*COUT + o];
    float sq = Sq[o] + Sq[COUT + o] + Sq[2*COUT + o] + Sq[3*COUT + o];
    gpart[(size_t)blockIdx.x * 2*COUT + o] = sm;
    gpart[(size_t)blockIdx.x * 2*COUT + COUT + o] = sq;
  }
}

// ---------------- finalize BN ----------------
__global__ __launch_bounds__(256) void bn_finalize_kernel(
    const float* __restrict__ gpart, int NB, int C,
    const float* __restrict__ g, const float* __restrict__ bb,
    float* __restrict__ sc, float* __restrict__ sh, float invN)
{
  int c = blockIdx.x;
  float sm = 0.f, sq = 0.f;
  for (int i = threadIdx.x; i < NB; i += 256){
    sm += gpart[(size_t)i*2*C + c];
    sq += gpart[(size_t)i*2*C + C + c];
  }
  #pragma unroll
  for (int off = 32; off > 0; off >>= 1){
    sm += __shfl_down(sm, off);
    sq += __shfl_down(sq, off);
  }
  __shared__ float rs[8];
  int wd = threadIdx.x >> 6, ln = threadIdx.x & 63;
  if (ln == 0){ rs[wd] = sm; rs[4+wd] = sq; }
  __syncthreads();
  if (threadIdx.x == 0){
    float S = rs[0]+rs[1]+rs[2]+rs[3], Q = rs[4]+rs[5]+rs[6]+rs[7];
    float mean = S * invN;
    float var  = fmaxf(Q * invN - mean*mean, 0.f);
    float s = g[c] * rsqrtf(var + 1e-5f);
    sc[c] = s;
    sh[c] = bb[c] - mean * s;
  }
}

// ------------- BN3 + relu + max-pool + write (16,64,N3) f32 -------------
__global__ __launch_bounds__(256) void pool_kernel(
    const unsigned short* __restrict__ h3, const int* __restrict__ pidx,
    const float* __restrict__ sc, const float* __restrict__ sh,
    float* __restrict__ out)
{
  __shared__ float P[16][1024];
  int m0 = blockIdx.x * 16;
  int tid = threadIdx.x;
  for (int mi = 0; mi < 16; mi++){
    int m = m0 + mi;
    int p0 = pidx[m*4+0], p1 = pidx[m*4+1], p2 = pidx[m*4+2], p3 = pidx[m*4+3];
    #pragma unroll
    for (int q = 0; q < 4; q++){
      int bo = tid + q*256;
      int o = bo & 63;
      float s = sc[o], h = sh[o];
      float v0 = fmaf(bf2f(h3[(size_t)p0*1024 + bo]), s, h);
      float v1 = fmaf(bf2f(h3[(size_t)p1*1024 + bo]), s, h);
      float v2 = fmaf(bf2f(h3[(size_t)p2*1024 + bo]), s, h);
      float v3 = fmaf(bf2f(h3[(size_t)p3*1024 + bo]), s, h);
      P[mi][bo] = fmaxf(fmaxf(fmaxf(v0,v1), fmaxf(v2,v3)), 0.f);
    }
  }
  __syncthreads();
  #pragma unroll
  for (int w = 0; w < 4; w++){
    int r = tid + w*256;
    float* dst = out + (size_t)r*N3C + m0;
    #pragma unroll
    for (int mi = 0; mi < 16; mi++) dst[mi] = P[mi][r];
  }
}

// ---------------- launch ----------------
extern "C" void kernel_launch(void* const* d_in, const int* in_sizes, int n_in,
                              void* d_out, int out_size, void* d_ws, size_t ws_size,
                              hipStream_t stream)
{
  const float* x    = (const float*)d_in[0];
  const float* l1   = (const float*)d_in[1];
  const float* l2   = (const float*)d_in[2];
  const int* knn1   = (const int*)d_in[4];
  const int* knn2   = (const int*)d_in[5];
  const int* knn3   = (const int*)d_in[6];
  const int* pidx   = (const int*)d_in[7];

  const float* c1_w1 = (const float*)d_in[8];
  const float* c1_b1 = (const float*)d_in[9];
  const float* c1_w2 = (const float*)d_in[10];
  const float* c1_b2 = (const float*)d_in[11];
  const float* c1_k  = (const float*)d_in[12];
  const float* c1_bs = (const float*)d_in[13];
  const float* c2_w1 = (const float*)d_in[14];
  const float* c2_b1 = (const float*)d_in[15];
  const float* c2_w2 = (const float*)d_in[16];
  const float* c2_b2 = (const float*)d_in[17];
  const float* c2_k  = (const float*)d_in[18];
  const float* c2_bs = (const float*)d_in[19];
  const float* c3_w1 = (const float*)d_in[20];
  const float* c3_b1 = (const float*)d_in[21];
  const float* c3_w2 = (const float*)d_in[22];
  const float* c3_b2 = (const float*)d_in[23];
  const float* c3_k  = (const float*)d_in[24];
  const float* c3_bs = (const float*)d_in[25];
  const float* bn1_g = (const float*)d_in[26];
  const float* bn1_b = (const float*)d_in[27];
  const float* bn2_g = (const float*)d_in[28];
  const float* bn2_b = (const float*)d_in[29];
  const float* bn3_g = (const float*)d_in[30];
  const float* bn3_b = (const float*)d_in[31];

  char* ws = (char*)d_ws;
  unsigned short* xTb = (unsigned short*)(ws + 0);
  unsigned short* h1  = (unsigned short*)(ws + 6422528);
  unsigned short* h2  = (unsigned short*)(ws + 19267584);
  unsigned short* h3  = (unsigned short*)(ws + 32112640);
  float* Abuf         = (float*)(ws + 57802752);
  float* gpart        = (float*)(ws + 61867008);
  unsigned short* wb1 = (unsigned short*)(ws + 65078272);
  unsigned short* wb2 = (unsigned short*)(ws + 65081344);
  unsigned short* wb3 = (unsigned short*)(ws + 65099776);
  float* sc1 = (float*)(ws + 65137664); float* sh1 = sc1 + 32;
  float* sc2 = sh1 + 32;                float* sh2 = sc2 + 32;
  float* sc3 = sh2 + 32;                float* sh3 = sc3 + 64;

  const float invN = 1.0f / (float)(N2C * 16);
  const int ablocks = (N2C * 9 + 255) / 256;

  transpose_x_kernel<<<N1C/64, 256, 0, stream>>>(x, xTb);
  wcvt_kernel<<<(32*32 + 255)/256, 256, 0, stream>>>(c1_k, wb1, 32*32, 27, 32);
  wcvt_kernel<<<(32*288 + 255)/256, 256, 0, stream>>>(c2_k, wb2, 32*288, 288, 288);
  wcvt_kernel<<<(64*288 + 255)/256, 256, 0, stream>>>(c3_k, wb3, 64*288, 288, 288);

  // conv1
  compute_A_kernel<<<ablocks, 256, 0, stream>>>(l1, l2, knn1, c1_w1, c1_b1, c1_w2, c1_b2, Abuf);
  conv_mfma_kernel<3, 4, 32, 8, false><<<N2C/8, 256, 0, stream>>>(
      xTb, knn1, Abuf, wb1, c1_bs, nullptr, nullptr, h1, gpart);
  bn_finalize_kernel<<<32, 256, 0, stream>>>(gpart, N2C/8, 32, bn1_g, bn1_b, sc1, sh1, invN);

  // conv2
  compute_A_kernel<<<ablocks, 256, 0, stream>>>(l2, l2, knn2, c2_w1, c2_b1, c2_w2, c2_b2, Abuf);
  conv_wave_kernel<32><<<N2C/4, 256, 0, stream>>>(
      h1, knn2, Abuf, wb2, c2_bs, sc1, sh1, h2, gpart);
  bn_finalize_kernel<<<32, 256, 0, stream>>>(gpart, N2C/4, 32, bn2_g, bn2_b, sc2, sh2, invN);

  // conv3
  compute_A_kernel<<<ablocks, 256, 0, stream>>>(l2, l2, knn3, c3_w1, c3_b1, c3_w2, c3_b2, Abuf);
  conv_wave_kernel<64><<<N2C/4, 256, 0, stream>>>(
      h2, knn3, Abuf, wb3, c3_bs, sc2, sh2, h3, gpart);
  bn_finalize_kernel<<<64, 256, 0, stream>>>(gpart, N2C/4, 64, bn3_g, bn3_b, sc3, sh3, invN);

  pool_kernel<<<N3C/16, 256, 0, stream>>>(h3, pidx, sc3, sh3, (float*)d_out);
}

// Round 6
// 169.154 us; speedup vs baseline: 4.3345x; 1.0396x over previous
//
#include <hip/hip_runtime.h>
#include <hip/hip_bf16.h>
#include <cfloat>

#define N1C 50176
#define N2C 12544
#define N3C 3136

typedef __attribute__((ext_vector_type(8))) short short8v;
typedef __attribute__((ext_vector_type(4))) float f32x4;

static __device__ __forceinline__ unsigned short f2bf(float f){
  __hip_bfloat16 h = __float2bfloat16(f);
  return *reinterpret_cast<unsigned short*>(&h);
}
static __device__ __forceinline__ float bflo(unsigned v){
  return __uint_as_float(v << 16);
}
static __device__ __forceinline__ float bfhi(unsigned v){
  return __uint_as_float(v & 0xFFFF0000u);
}
static __device__ __forceinline__ float bf2f(unsigned short u){
  return __uint_as_float(((unsigned)u) << 16);
}

// ---------------- transpose x: (16,3,N1) f32 -> xTb (N1, 16, 4) bf16 ----
__global__ __launch_bounds__(256) void transpose_x_kernel(
    const float* __restrict__ x, unsigned short* __restrict__ xTb)
{
  __shared__ float tile[48][65];
  int n0 = blockIdx.x * 64;
  int tid = threadIdx.x;
  int i = tid & 63;
  for (int rr = tid >> 6; rr < 48; rr += 4)
    tile[rr][i] = x[(size_t)rr * N1C + n0 + i];
  __syncthreads();
  for (int j = tid; j < 64*64; j += 256){
    int ii = j >> 6, bc = j & 63, b = bc >> 2, c = bc & 3;
    float v = (c < 3) ? tile[b*3 + c][ii] : 0.f;
    xTb[(size_t)n0 * 64 + j] = f2bf(v);
  }
}

// ---------------- A[n,k,t] = (relu(off @ w1 + b1) @ w2 + b2) ----------------
__global__ __launch_bounds__(256) void compute_A_kernel(
    const float* __restrict__ pos_in, const float* __restrict__ pos_out,
    const int* __restrict__ idx,
    const float* __restrict__ w1, const float* __restrict__ b1,
    const float* __restrict__ w2, const float* __restrict__ b2,
    float* __restrict__ Abuf)
{
  int g = blockIdx.x * 256 + threadIdx.x;
  if (g >= N2C * 9) return;
  int n = g / 9;
  int p = idx[g];
  float o0 = pos_in[2*p]   - pos_out[2*n];
  float o1 = pos_in[2*p+1] - pos_out[2*n+1];
  float A[9];
  #pragma unroll
  for (int t = 0; t < 9; t++) A[t] = b2[t];
  #pragma unroll
  for (int j = 0; j < 16; j++){
    float h = fmaxf(fmaf(o0, w1[j], fmaf(o1, w1[16+j], b1[j])), 0.f);
    #pragma unroll
    for (int t = 0; t < 9; t++) A[t] = fmaf(h, w2[j*9 + t], A[t]);
  }
  #pragma unroll
  for (int t = 0; t < 9; t++) Abuf[(size_t)g*9 + t] = A[t];
}

// ---------------- W (o,k) f32 -> Wb[o][k] bf16, zero-padded to KW --------
__global__ __launch_bounds__(256) void wcvt_kernel(
    const float* __restrict__ W, unsigned short* __restrict__ Wb,
    int total, int K, int KW)
{
  int i = blockIdx.x * 256 + threadIdx.x;
  if (i >= total) return;
  int o = i / KW, k = i % KW;
  Wb[i] = f2bf(k < K ? W[o*K + k] : 0.f);
}

// ======== conv1 path (small CIN) ========
template<int CIN, int CINP, int COUT, int NPB, bool AFFINE>
__global__ __launch_bounds__(256) void conv_mfma_kernel(
    const unsigned short* __restrict__ in, const int* __restrict__ idx,
    const float* __restrict__ Abuf, const unsigned short* __restrict__ Wb,
    const float* __restrict__ bias,
    const float* __restrict__ scale, const float* __restrict__ shift,
    unsigned short* __restrict__ out, float* __restrict__ gpart)
{
  constexpr int K    = CIN * 9;
  constexpr int KW   = (K < 32) ? 32 : K;
  constexpr int KROW = (K < 32) ? 48 : 296;
  constexpr int CHUNKS = KW / 32;
  constexpr int OT   = COUT / 16;
  constexpr int HP   = CINP / 2;
  constexpr int PPT  = 16 * HP;

  __shared__ alignas(16) unsigned short Tb[NPB * 16 * KROW];
  __shared__ float As[NPB * 81];
  __shared__ int   Ip[NPB * 9];
  __shared__ float Sw[4 * COUT];
  __shared__ float Sq[4 * COUT];

  int n0 = blockIdx.x * NPB;
  int tid = threadIdx.x;
  for (int i = tid; i < NPB*81; i += 256) As[i] = Abuf[(size_t)n0*81 + i];
  if (tid < NPB*9) Ip[tid] = idx[n0*9 + tid];
  for (int i = tid; i < 4*COUT; i += 256){ Sw[i] = 0.f; Sq[i] = 0.f; }
  if (K < 32){
    for (int i = tid; i < NPB*16*KROW/2; i += 256) ((unsigned*)Tb)[i] = 0u;
  }
  __syncthreads();

  for (int u = tid; u < NPB*PPT; u += 256){
    int ni = u / PPT, loc = u % PPT;
    int b = loc / HP, c2 = loc % HP;
    const float* As_n = As + ni*81;
    const int*   ip   = Ip + ni*9;
    float scx=1.f, shx=0.f, scy=1.f, shy=0.f;
    if (AFFINE){
      scx = scale[2*c2];   shx = shift[2*c2];
      scy = scale[2*c2+1]; shy = shift[2*c2+1];
    }
    float fx[9], fy[9];
    #pragma unroll
    for (int k = 0; k < 9; k++){
      unsigned v = *(const unsigned*)(in + ((size_t)ip[k]*16 + b)*CINP + 2*c2);
      float x0 = bflo(v), y0 = bfhi(v);
      if (AFFINE){
        x0 = fmaxf(fmaf(x0, scx, shx), 0.f);
        y0 = fmaxf(fmaf(y0, scy, shy), 0.f);
      }
      fx[k] = x0; fy[k] = y0;
    }
    unsigned short e[18];
    #pragma unroll
    for (int t = 0; t < 9; t++){
      float s0 = 0.f, s1 = 0.f;
      #pragma unroll
      for (int k = 0; k < 9; k++){
        float a = As_n[k*9 + t];
        s0 = fmaf(fx[k], a, s0);
        s1 = fmaf(fy[k], a, s1);
      }
      e[t] = f2bf(s0); e[9+t] = f2bf(s1);
    }
    unsigned* dst = (unsigned*)(Tb + (ni*16 + b)*KROW + 18*c2);
    #pragma unroll
    for (int j = 0; j < 9; j++) dst[j] = (unsigned)e[2*j] | ((unsigned)e[2*j+1] << 16);
  }
  __syncthreads();

  int w = tid >> 6, l = tid & 63, lr = l & 15, lg = l >> 4;
  float smr[4] = {0,0,0,0}, sqr[4] = {0,0,0,0};
  int oBase = 0;
  for (int wi = w; wi < NPB*OT; wi += 4){
    int ni = wi / OT, ot = wi % OT;
    oBase = 16*ot + 4*lg;
    f32x4 acc;
    #pragma unroll
    for (int r = 0; r < 4; r++) acc[r] = bias[oBase + r];
    const short8v* ap = (const short8v*)(Wb + (size_t)(16*ot + lr)*KW) + lg;
    const short8v* bp = (const short8v*)(Tb + (ni*16 + lr)*KROW) + lg;
    #pragma unroll
    for (int kk = 0; kk < CHUNKS; kk++)
      acc = __builtin_amdgcn_mfma_f32_16x16x32_bf16(ap[kk*4], bp[kk*4], acc, 0, 0, 0);
    ushort4 o4;
    o4.x = f2bf(acc[0]); o4.y = f2bf(acc[1]); o4.z = f2bf(acc[2]); o4.w = f2bf(acc[3]);
    *(ushort4*)(out + ((size_t)(n0 + ni)*16 + lr)*COUT + oBase) = o4;
    #pragma unroll
    for (int r = 0; r < 4; r++){
      smr[r] += acc[r];
      sqr[r] = fmaf(acc[r], acc[r], sqr[r]);
    }
  }
  #pragma unroll
  for (int m = 1; m < 16; m <<= 1){
    #pragma unroll
    for (int r = 0; r < 4; r++){
      smr[r] += __shfl_xor(smr[r], m);
      sqr[r] += __shfl_xor(sqr[r], m);
    }
  }
  if (lr == 0){
    #pragma unroll
    for (int r = 0; r < 4; r++){
      Sw[w*COUT + oBase + r] = smr[r];
      Sq[w*COUT + oBase + r] = sqr[r];
    }
  }
  __syncthreads();
  for (int o = tid; o < COUT; o += 256){
    float sm = Sw[o] + Sw[COUT + o] + Sw[2*COUT + o] + Sw[3*COUT + o];
    float sq = Sq[o] + Sq[COUT + o] + Sq[2*COUT + o] + Sq[3*COUT + o];
    gpart[(size_t)blockIdx.x * 2*COUT + o] = sm;
    gpart[(size_t)blockIdx.x * 2*COUT + COUT + o] = sq;
  }
}

// ======== conv2/3: wave-per-point, barrier-free, 2-pass channels ========
// in: (N2, 16, 32) bf16; out: (N2, 16, COUT) bf16. CIN=32, AFFINE.
template<int COUT>
__global__ __launch_bounds__(256, 4) void conv_wave_kernel(
    const unsigned short* __restrict__ in, const int* __restrict__ idx,
    const float* __restrict__ Abuf, const unsigned short* __restrict__ Wb,
    const float* __restrict__ bias,
    const float* __restrict__ scale, const float* __restrict__ shift,
    unsigned short* __restrict__ out, float* __restrict__ gpart)
{
  constexpr int NPB  = 4;
  constexpr int KROW = 296;
  constexpr int OT   = COUT / 16;

  __shared__ alignas(16) unsigned short Tb[NPB * 16 * KROW];  // 37,888 B
  __shared__ float Sw[4 * COUT];
  __shared__ float Sq[4 * COUT];

  int tid = threadIdx.x;
  int w = tid >> 6, l = tid & 63;
  int n0 = blockIdx.x * NPB;

  int nws = __builtin_amdgcn_readfirstlane(n0 + w);

  // A[81] (wave-uniform -> scalar loads)
  float areg[81];
  {
    const float* Ap = Abuf + (size_t)nws * 81;
    #pragma unroll
    for (int j = 0; j < 81; j++) areg[j] = Ap[j];
  }
  int ip[9];
  {
    const int* ipr = idx + nws * 9;
    #pragma unroll
    for (int k = 0; k < 9; k++) ip[k] = ipr[k];
  }

  // ---- phase 2: lane = (b, 8-channel group); 9x dwordx4 gather ----
  int b = l & 15, cg = l >> 4;
  float4 scA = *(const float4*)(scale + cg*8);
  float4 scB = *(const float4*)(scale + cg*8 + 4);
  float4 shA = *(const float4*)(shift + cg*8);
  float4 shB = *(const float4*)(shift + cg*8 + 4);

  uint4 rv[9];
  #pragma unroll
  for (int k = 0; k < 9; k++){
    const unsigned short* rp = in + (size_t)ip[k]*512 + b*32 + cg*8;
    rv[k] = *(const uint4*)rp;
  }

  // two half-passes of 4 channels each: acc[36] live instead of acc[72]
  #pragma unroll
  for (int h = 0; h < 2; h++){
    float sc[4], sh[4];
    if (h == 0){
      sc[0]=scA.x; sc[1]=scA.y; sc[2]=scA.z; sc[3]=scA.w;
      sh[0]=shA.x; sh[1]=shA.y; sh[2]=shA.z; sh[3]=shA.w;
    } else {
      sc[0]=scB.x; sc[1]=scB.y; sc[2]=scB.z; sc[3]=scB.w;
      sh[0]=shB.x; sh[1]=shB.y; sh[2]=shB.z; sh[3]=shB.w;
    }
    float acc[36];
    #pragma unroll
    for (int i = 0; i < 36; i++) acc[i] = 0.f;
    #pragma unroll
    for (int k = 0; k < 9; k++){
      unsigned u0 = (h == 0) ? rv[k].x : rv[k].z;
      unsigned u1 = (h == 0) ? rv[k].y : rv[k].w;
      float c0 = fmaxf(fmaf(bflo(u0), sc[0], sh[0]), 0.f);
      float c1 = fmaxf(fmaf(bfhi(u0), sc[1], sh[1]), 0.f);
      float c2 = fmaxf(fmaf(bflo(u1), sc[2], sh[2]), 0.f);
      float c3 = fmaxf(fmaf(bfhi(u1), sc[3], sh[3]), 0.f);
      #pragma unroll
      for (int t = 0; t < 9; t++){
        float a = areg[k*9 + t];
        acc[t]      = fmaf(c0, a, acc[t]);
        acc[9 + t]  = fmaf(c1, a, acc[9 + t]);
        acc[18 + t] = fmaf(c2, a, acc[18 + t]);
        acc[27 + t] = fmaf(c3, a, acc[27 + t]);
      }
    }
    // pack 36 f32 -> 36 bf16 (72 B), 9x ds_write_b64
    uint2* du = (uint2*)(Tb + (size_t)(w*16 + b)*KROW + cg*72 + h*36);
    #pragma unroll
    for (int q = 0; q < 9; q++){
      uint2 o;
      o.x = (unsigned)f2bf(acc[4*q+0]) | ((unsigned)f2bf(acc[4*q+1]) << 16);
      o.y = (unsigned)f2bf(acc[4*q+2]) | ((unsigned)f2bf(acc[4*q+3]) << 16);
      du[q] = o;
    }
  }

  // ---- phase 3: wave-local (ni = w), no block barrier needed ----
  int lr = l & 15, lg = l >> 4;
  const short8v* bp = (const short8v*)(Tb + (size_t)(w*16 + lr)*KROW) + lg;
  #pragma unroll
  for (int ot = 0; ot < OT; ot++){
    int oBase = 16*ot + 4*lg;
    f32x4 a3;
    #pragma unroll
    for (int r = 0; r < 4; r++) a3[r] = bias[oBase + r];
    const short8v* ap = (const short8v*)(Wb + (size_t)(16*ot + lr)*288) + lg;
    #pragma unroll
    for (int kk = 0; kk < 9; kk++)
      a3 = __builtin_amdgcn_mfma_f32_16x16x32_bf16(ap[kk*4], bp[kk*4], a3, 0, 0, 0);
    ushort4 o4;
    o4.x = f2bf(a3[0]); o4.y = f2bf(a3[1]); o4.z = f2bf(a3[2]); o4.w = f2bf(a3[3]);
    *(ushort4*)(out + ((size_t)(n0 + w)*16 + lr)*COUT + oBase) = o4;

    float smr[4], sqr[4];
    #pragma unroll
    for (int r = 0; r < 4; r++){ smr[r] = a3[r]; sqr[r] = a3[r]*a3[r]; }
    #pragma unroll
    for (int m = 1; m < 16; m <<= 1){
      #pragma unroll
      for (int r = 0; r < 4; r++){
        smr[r] += __shfl_xor(smr[r], m);
        sqr[r] += __shfl_xor(sqr[r], m);
      }
    }
    if (lr == 0){
      #pragma unroll
      for (int r = 0; r < 4; r++){
        Sw[w*COUT + oBase + r] = smr[r];
        Sq[w*COUT + oBase + r] = sqr[r];
      }
    }
  }
  __syncthreads();
  for (int o = tid; o < COUT; o += 256){
    float sm = Sw[o] + Sw[COUT + o] + Sw[2*COUT + o] + Sw[3*COUT + o];
    float sq = Sq[o] + Sq[COUT + o] + Sq[2*COUT + o] + Sq[3*COUT + o];
    gpart[(size_t)blockIdx.x * 2*COUT + o] = sm;
    gpart[(size_t)blockIdx.x * 2*COUT + COUT + o] = sq;
  }
}

// ---------------- finalize BN ----------------
__global__ __launch_bounds__(256) void bn_finalize_kernel(
    const float* __restrict__ gpart, int NB, int C,
    const float* __restrict__ g, const float* __restrict__ bb,
    float* __restrict__ sc, float* __restrict__ sh, float invN)
{
  int c = blockIdx.x;
  float sm = 0.f, sq = 0.f;
  for (int i = threadIdx.x; i < NB; i += 256){
    sm += gpart[(size_t)i*2*C + c];
    sq += gpart[(size_t)i*2*C + C + c];
  }
  #pragma unroll
  for (int off = 32; off > 0; off >>= 1){
    sm += __shfl_down(sm, off);
    sq += __shfl_down(sq, off);
  }
  __shared__ float rs[8];
  int wd = threadIdx.x >> 6, ln = threadIdx.x & 63;
  if (ln == 0){ rs[wd] = sm; rs[4+wd] = sq; }
  __syncthreads();
  if (threadIdx.x == 0){
    float S = rs[0]+rs[1]+rs[2]+rs[3], Q = rs[4]+rs[5]+rs[6]+rs[7];
    float mean = S * invN;
    float var  = fmaxf(Q * invN - mean*mean, 0.f);
    float s = g[c] * rsqrtf(var + 1e-5f);
    sc[c] = s;
    sh[c] = bb[c] - mean * s;
  }
}

// ------------- BN3 + relu + max-pool + write (16,64,N3) f32 -------------
__global__ __launch_bounds__(256) void pool_kernel(
    const unsigned short* __restrict__ h3, const int* __restrict__ pidx,
    const float* __restrict__ sc, const float* __restrict__ sh,
    float* __restrict__ out)
{
  __shared__ float P[16][1024];
  int m0 = blockIdx.x * 16;
  int tid = threadIdx.x;
  for (int mi = 0; mi < 16; mi++){
    int m = m0 + mi;
    int p0 = pidx[m*4+0], p1 = pidx[m*4+1], p2 = pidx[m*4+2], p3 = pidx[m*4+3];
    #pragma unroll
    for (int q = 0; q < 4; q++){
      int bo = tid + q*256;
      int o = bo & 63;
      float s = sc[o], h = sh[o];
      float v0 = fmaf(bf2f(h3[(size_t)p0*1024 + bo]), s, h);
      float v1 = fmaf(bf2f(h3[(size_t)p1*1024 + bo]), s, h);
      float v2 = fmaf(bf2f(h3[(size_t)p2*1024 + bo]), s, h);
      float v3 = fmaf(bf2f(h3[(size_t)p3*1024 + bo]), s, h);
      P[mi][bo] = fmaxf(fmaxf(fmaxf(v0,v1), fmaxf(v2,v3)), 0.f);
    }
  }
  __syncthreads();
  #pragma unroll
  for (int w = 0; w < 4; w++){
    int r = tid + w*256;
    float* dst = out + (size_t)r*N3C + m0;
    #pragma unroll
    for (int mi = 0; mi < 16; mi++) dst[mi] = P[mi][r];
  }
}

// ---------------- launch ----------------
extern "C" void kernel_launch(void* const* d_in, const int* in_sizes, int n_in,
                              void* d_out, int out_size, void* d_ws, size_t ws_size,
                              hipStream_t stream)
{
  const float* x    = (const float*)d_in[0];
  const float* l1   = (const float*)d_in[1];
  const float* l2   = (const float*)d_in[2];
  const int* knn1   = (const int*)d_in[4];
  const int* knn2   = (const int*)d_in[5];
  const int* knn3   = (const int*)d_in[6];
  const int* pidx   = (const int*)d_in[7];

  const float* c1_w1 = (const float*)d_in[8];
  const float* c1_b1 = (const float*)d_in[9];
  const float* c1_w2 = (const float*)d_in[10];
  const float* c1_b2 = (const float*)d_in[11];
  const float* c1_k  = (const float*)d_in[12];
  const float* c1_bs = (const float*)d_in[13];
  const float* c2_w1 = (const float*)d_in[14];
  const float* c2_b1 = (const float*)d_in[15];
  const float* c2_w2 = (const float*)d_in[16];
  const float* c2_b2 = (const float*)d_in[17];
  const float* c2_k  = (const float*)d_in[18];
  const float* c2_bs = (const float*)d_in[19];
  const float* c3_w1 = (const float*)d_in[20];
  const float* c3_b1 = (const float*)d_in[21];
  const float* c3_w2 = (const float*)d_in[22];
  const float* c3_b2 = (const float*)d_in[23];
  const float* c3_k  = (const float*)d_in[24];
  const float* c3_bs = (const float*)d_in[25];
  const float* bn1_g = (const float*)d_in[26];
  const float* bn1_b = (const float*)d_in[27];
  const float* bn2_g = (const float*)d_in[28];
  const float* bn2_b = (const float*)d_in[29];
  const float* bn3_g = (const float*)d_in[30];
  const float* bn3_b = (const float*)d_in[31];

  char* ws = (char*)d_ws;
  unsigned short* xTb = (unsigned short*)(ws + 0);
  unsigned short* h1  = (unsigned short*)(ws + 6422528);
  unsigned short* h2  = (unsigned short*)(ws + 19267584);
  unsigned short* h3  = (unsigned short*)(ws + 32112640);
  float* Abuf         = (float*)(ws + 57802752);
  float* gpart        = (float*)(ws + 61867008);
  unsigned short* wb1 = (unsigned short*)(ws + 65078272);
  unsigned short* wb2 = (unsigned short*)(ws + 65081344);
  unsigned short* wb3 = (unsigned short*)(ws + 65099776);
  float* sc1 = (float*)(ws + 65137664); float* sh1 = sc1 + 32;
  float* sc2 = sh1 + 32;                float* sh2 = sc2 + 32;
  float* sc3 = sh2 + 32;                float* sh3 = sc3 + 64;

  const float invN = 1.0f / (float)(N2C * 16);
  const int ablocks = (N2C * 9 + 255) / 256;

  transpose_x_kernel<<<N1C/64, 256, 0, stream>>>(x, xTb);
  wcvt_kernel<<<(32*32 + 255)/256, 256, 0, stream>>>(c1_k, wb1, 32*32, 27, 32);
  wcvt_kernel<<<(32*288 + 255)/256, 256, 0, stream>>>(c2_k, wb2, 32*288, 288, 288);
  wcvt_kernel<<<(64*288 + 255)/256, 256, 0, stream>>>(c3_k, wb3, 64*288, 288, 288);

  // conv1
  compute_A_kernel<<<ablocks, 256, 0, stream>>>(l1, l2, knn1, c1_w1, c1_b1, c1_w2, c1_b2, Abuf);
  conv_mfma_kernel<3, 4, 32, 8, false><<<N2C/8, 256, 0, stream>>>(
      xTb, knn1, Abuf, wb1, c1_bs, nullptr, nullptr, h1, gpart);
  bn_finalize_kernel<<<32, 256, 0, stream>>>(gpart, N2C/8, 32, bn1_g, bn1_b, sc1, sh1, invN);

  // conv2
  compute_A_kernel<<<ablocks, 256, 0, stream>>>(l2, l2, knn2, c2_w1, c2_b1, c2_w2, c2_b2, Abuf);
  conv_wave_kernel<32><<<N2C/4, 256, 0, stream>>>(
      h1, knn2, Abuf, wb2, c2_bs, sc1, sh1, h2, gpart);
  bn_finalize_kernel<<<32, 256, 0, stream>>>(gpart, N2C/4, 32, bn2_g, bn2_b, sc2, sh2, invN);

  // conv3
  compute_A_kernel<<<ablocks, 256, 0, stream>>>(l2, l2, knn3, c3_w1, c3_b1, c3_w2, c3_b2, Abuf);
  conv_wave_kernel<64><<<N2C/4, 256, 0, stream>>>(
      h2, knn3, Abuf, wb3, c3_bs, sc2, sh2, h3, gpart);
  bn_finalize_kernel<<<64, 256, 0, stream>>>(gpart, N2C/4, 64, bn3_g, bn3_b, sc3, sh3, invN);

  pool_kernel<<<N3C/16, 256, 0, stream>>>(h3, pidx, sc3, sh3, (float*)d_out);
}